// Round 2
// baseline (2333.523 us; speedup 1.0000x reference)
//
#include <hip/hip_runtime.h>
#include <hip/hip_bf16.h>
#include <math.h>
#include <stddef.h>

#define CS 2048   // S
#define CD 768    // D
#define CH 12     // H
#define CDH 64    // DH
#define CF 3072   // F
#define CW 256    // W
#define CNC 8     // NC
#define CL 2      // L

// ---------------- block reduction (256 threads = 4 waves) ----------------
__device__ __forceinline__ float block_reduce_sum(float v, float* buf) {
  #pragma unroll
  for (int off = 32; off > 0; off >>= 1) v += __shfl_down(v, off, 64);
  int wid = threadIdx.x >> 6;
  __syncthreads();                 // protect buf reuse across calls
  if ((threadIdx.x & 63) == 0) buf[wid] = v;
  __syncthreads();
  if (threadIdx.x == 0) buf[0] = buf[0] + buf[1] + buf[2] + buf[3];
  __syncthreads();
  return buf[0];
}

// ---------------- pos_ids = cumsum(mask)*mask + 1 ----------------
__global__ __launch_bounds__(256) void scan_kernel(const int* __restrict__ mask,
                                                   int* __restrict__ pos) {
  __shared__ int part[256];
  int tid = threadIdx.x;
  int mv[8]; int s = 0;
  #pragma unroll
  for (int i = 0; i < 8; ++i) { mv[i] = mask[tid * 8 + i]; s += mv[i]; }
  part[tid] = s;
  __syncthreads();
  for (int off = 1; off < 256; off <<= 1) {
    int t = 0;
    if (tid >= off) t = part[tid - off];
    __syncthreads();
    part[tid] += t;
    __syncthreads();
  }
  int run = part[tid] - s;  // exclusive prefix
  #pragma unroll
  for (int i = 0; i < 8; ++i) {
    run += mv[i];
    pos[tid * 8 + i] = run * mv[i] + 1;
  }
}

// ---------------- embedding gather + LN ----------------
__global__ __launch_bounds__(256) void embed_ln_kernel(
    const int* __restrict__ ids, const int* __restrict__ pos,
    const float* __restrict__ wemb, const float* __restrict__ pemb,
    const float* __restrict__ temb, const float* __restrict__ gs,
    const float* __restrict__ gb, float* __restrict__ x) {
  __shared__ float red[4];
  int srow = blockIdx.x;
  long long id = ids[srow];
  long long pid = pos[srow];
  float v[3];
  #pragma unroll
  for (int i = 0; i < 3; ++i) {
    int d = threadIdx.x + i * 256;
    v[i] = wemb[id * CD + d] + pemb[pid * CD + d] + temb[d];
  }
  float sum = v[0] + v[1] + v[2];
  sum = block_reduce_sum(sum, red);
  float mean = sum * (1.0f / CD);
  float sq = 0.f;
  #pragma unroll
  for (int i = 0; i < 3; ++i) { float c = v[i] - mean; sq += c * c; }
  sq = block_reduce_sum(sq, red);
  float rstd = rsqrtf(sq * (1.0f / CD) + 1e-5f);
  #pragma unroll
  for (int i = 0; i < 3; ++i) {
    int d = threadIdx.x + i * 256;
    x[(size_t)srow * CD + d] = (v[i] - mean) * rstd * gs[d] + gb[d];
  }
}

// ---------------- generic GEMM: C = A(f32, MxK) * B(f32, KxN) + bias ----------------
template<int GELU>
__global__ __launch_bounds__(256) void gemm_kernel(
    const float* __restrict__ A, const float* __restrict__ B,
    const float* __restrict__ bias, float* __restrict__ C,
    int M, int N, int K) {
  __shared__ float As[16][65];  // transposed, padded
  __shared__ float Bs[16][64];
  int tid = threadIdx.x;
  int tx = tid & 15, ty = tid >> 4;
  int m0 = blockIdx.y * 64, n0 = blockIdx.x * 64;
  int a_row = tid >> 2, a_col = (tid & 3) << 2;
  int b_row = tid >> 4, b_col = (tid & 15) << 2;
  const float* Aptr = A + (size_t)(m0 + a_row) * K + a_col;
  const float* Bptr = B + (size_t)b_row * N + n0 + b_col;
  float acc[4][4] = {};
  for (int k0 = 0; k0 < K; k0 += 16) {
    float4 av = *(const float4*)(Aptr + k0);
    float4 bv = *(const float4*)(Bptr + (size_t)k0 * N);
    As[a_col + 0][a_row] = av.x;
    As[a_col + 1][a_row] = av.y;
    As[a_col + 2][a_row] = av.z;
    As[a_col + 3][a_row] = av.w;
    *(float4*)&Bs[b_row][b_col] = bv;
    __syncthreads();
    #pragma unroll
    for (int kk = 0; kk < 16; ++kk) {
      float a[4], b[4];
      #pragma unroll
      for (int i = 0; i < 4; ++i) a[i] = As[kk][ty * 4 + i];
      #pragma unroll
      for (int j = 0; j < 4; ++j) b[j] = Bs[kk][tx * 4 + j];
      #pragma unroll
      for (int i = 0; i < 4; ++i)
        #pragma unroll
        for (int j = 0; j < 4; ++j)
          acc[i][j] = fmaf(a[i], b[j], acc[i][j]);
    }
    __syncthreads();
  }
  #pragma unroll
  for (int i = 0; i < 4; ++i) {
    int m = m0 + ty * 4 + i;
    #pragma unroll
    for (int j = 0; j < 4; ++j) {
      int n = n0 + tx * 4 + j;
      float v = acc[i][j] + bias[n];
      if (GELU) v = 0.5f * v * (1.0f + erff(v * 0.70710678118654752f));
      C[(size_t)m * N + n] = v;
    }
  }
}

// ---------------- banded attention, one (chunk, head) per block ----------------
// 64-key tiles: Ks/Vs = 2 * 64*64*4 B = 32 KB LDS (safe under any per-WG limit)
__global__ __launch_bounds__(256) void attn_kernel(
    const float* __restrict__ q, const float* __restrict__ k,
    const float* __restrict__ v, const int* __restrict__ mask,
    float* __restrict__ ctx) {
  __shared__ float Ks[64][64];
  __shared__ float Vs[64][64];
  __shared__ float vmask[64];
  int c = blockIdx.x;   // chunk
  int h = blockIdx.y;   // head
  int w = threadIdx.x;  // query row within chunk
  int qrow = c * CW + w;
  const float* qp = &q[(size_t)qrow * CD + h * CDH];
  float qreg[64];
  #pragma unroll
  for (int d = 0; d < 64; d += 4) {
    float4 t = *(const float4*)&qp[d];
    qreg[d] = t.x; qreg[d + 1] = t.y; qreg[d + 2] = t.z; qreg[d + 3] = t.w;
  }
  float m = -1e30f, l = 0.f;
  float o[64] = {};
  #pragma unroll 1
  for (int t0 = 0; t0 < 3 * CW; t0 += 64) {
    __syncthreads();
    // stage 64 keys + values (f32) into LDS, float4 coalesced
    #pragma unroll 1
    for (int i = 0; i < 4; ++i) {
      int idx = i * 256 + threadIdx.x;   // 0..1023 float4s
      int row = idx >> 4, col = (idx & 15) << 2;
      int p = c * CW + t0 + row - CW;    // real key position
      if (p >= 0 && p < CS) {
        float4 kv = *(const float4*)&k[(size_t)p * CD + h * CDH + col];
        float4 vv = *(const float4*)&v[(size_t)p * CD + h * CDH + col];
        *(float4*)&Ks[row][col] = kv;
        *(float4*)&Vs[row][col] = vv;
      } else {
        float4 z = {0.f, 0.f, 0.f, 0.f};
        *(float4*)&Ks[row][col] = z;
        *(float4*)&Vs[row][col] = z;
      }
    }
    if (threadIdx.x < 64) {
      int p = c * CW + t0 + threadIdx.x - CW;
      vmask[threadIdx.x] = (p >= 0 && p < CS && mask[p] != 0) ? 1.f : 0.f;
    }
    __syncthreads();
    #pragma unroll 1
    for (int jj = 0; jj < 64; ++jj) {
      int j = t0 + jj;
      const float4* krow = (const float4*)&Ks[jj][0];
      float dot = 0.f;
      #pragma unroll
      for (int dd = 0; dd < 16; ++dd) {
        float4 kv = krow[dd];
        dot = fmaf(qreg[4 * dd + 0], kv.x, dot);
        dot = fmaf(qreg[4 * dd + 1], kv.y, dot);
        dot = fmaf(qreg[4 * dd + 2], kv.z, dot);
        dot = fmaf(qreg[4 * dd + 3], kv.w, dot);
      }
      bool band = (j >= w) && (j <= w + 2 * CW);
      float s = (band && vmask[jj] > 0.5f) ? dot * 0.125f : -1e9f;
      if (s > m) {                 // rescale-on-demand
        float fac = __expf(m - s);
        l *= fac;
        #pragma unroll
        for (int d = 0; d < 64; ++d) o[d] *= fac;
        m = s;
      }
      float pr = __expf(s - m);
      l += pr;
      const float4* vrow = (const float4*)&Vs[jj][0];
      #pragma unroll
      for (int dd = 0; dd < 16; ++dd) {
        float4 vv = vrow[dd];
        o[4 * dd + 0] = fmaf(pr, vv.x, o[4 * dd + 0]);
        o[4 * dd + 1] = fmaf(pr, vv.y, o[4 * dd + 1]);
        o[4 * dd + 2] = fmaf(pr, vv.z, o[4 * dd + 2]);
        o[4 * dd + 3] = fmaf(pr, vv.w, o[4 * dd + 3]);
      }
    }
  }
  float inv = 1.0f / l;
  float* op = &ctx[(size_t)qrow * CD + h * CDH];
  #pragma unroll
  for (int d = 0; d < 64; ++d) op[d] = o[d] * inv;
}

// ---------------- x = LN(x + g) ----------------
__global__ __launch_bounds__(256) void add_ln_kernel(
    const float* __restrict__ g, float* __restrict__ x,
    const float* __restrict__ gs, const float* __restrict__ gb) {
  __shared__ float red[4];
  int srow = blockIdx.x;
  float v[3];
  #pragma unroll
  for (int i = 0; i < 3; ++i) {
    int d = threadIdx.x + i * 256;
    v[i] = g[(size_t)srow * CD + d] + x[(size_t)srow * CD + d];
  }
  float sum = v[0] + v[1] + v[2];
  sum = block_reduce_sum(sum, red);
  float mean = sum * (1.0f / CD);
  float sq = 0.f;
  #pragma unroll
  for (int i = 0; i < 3; ++i) { float c = v[i] - mean; sq += c * c; }
  sq = block_reduce_sum(sq, red);
  float rstd = rsqrtf(sq * (1.0f / CD) + 1e-5f);
  #pragma unroll
  for (int i = 0; i < 3; ++i) {
    int d = threadIdx.x + i * 256;
    x[(size_t)srow * CD + d] = (v[i] - mean) * rstd * gs[d] + gb[d];
  }
}

// ---------------- x (f32) -> out (f32) ----------------
__global__ __launch_bounds__(256) void finalize_kernel(const float* __restrict__ x,
                                                       float* __restrict__ out) {
  int i = blockIdx.x * 256 + threadIdx.x;
  out[i] = x[i];
}

// ---------------- pooled = tanh(x[0] @ pool_W + pool_b) ----------------
__global__ __launch_bounds__(256) void pool_kernel(
    const float* __restrict__ x, const float* __restrict__ Wp,
    const float* __restrict__ bp, float* __restrict__ out) {
  __shared__ float xs[CD];
  for (int i = threadIdx.x; i < CD; i += 256) xs[i] = x[i];
  __syncthreads();
  for (int n = threadIdx.x; n < CD; n += 256) {
    float acc = bp[n];
    for (int kk = 0; kk < CD; ++kk) acc = fmaf(xs[kk], Wp[(size_t)kk * CD + n], acc);
    out[n] = tanhf(acc);
  }
}

extern "C" void kernel_launch(void* const* d_in, const int* in_sizes, int n_in,
                              void* d_out, int out_size, void* d_ws, size_t ws_size,
                              hipStream_t stream) {
  const int*   ids   = (const int*)d_in[0];
  const int*   mask  = (const int*)d_in[1];
  const float* wemb  = (const float*)d_in[2];
  const float* pemb  = (const float*)d_in[3];
  const float* temb  = (const float*)d_in[4];
  const float* elns  = (const float*)d_in[5];
  const float* elnb  = (const float*)d_in[6];
  const float* Wqkv  = (const float*)d_in[7];
  const float* bqkv  = (const float*)d_in[8];
  const float* Wo    = (const float*)d_in[9];
  const float* bo    = (const float*)d_in[10];
  const float* ln1s  = (const float*)d_in[11];
  const float* ln1b  = (const float*)d_in[12];
  const float* W1    = (const float*)d_in[13];
  const float* b1    = (const float*)d_in[14];
  const float* W2    = (const float*)d_in[15];
  const float* b2    = (const float*)d_in[16];
  const float* ln2s  = (const float*)d_in[17];
  const float* ln2b  = (const float*)d_in[18];
  const float* poolW = (const float*)d_in[19];
  const float* poolb = (const float*)d_in[20];

  const size_t SD = (size_t)CS * CD;   // 1,572,864
  const size_t SF = (size_t)CS * CF;   // 6,291,456
  float* x   = (float*)d_ws;
  float* qb  = x + SD;
  float* kb  = qb + SD;
  float* vb  = kb + SD;
  float* ctx = vb + SD;
  float* t1  = ctx + SD;      // S x F
  float* t2  = t1 + SF;       // S x D
  int*   pos = (int*)(t2 + SD);

  dim3 gD(CD / 64, CS / 64);  // (12, 32)
  dim3 gF(CF / 64, CS / 64);  // (48, 32)

  scan_kernel<<<1, 256, 0, stream>>>(mask, pos);
  embed_ln_kernel<<<CS, 256, 0, stream>>>(ids, pos, wemb, pemb, temb, elns, elnb, x);

  for (int l = 0; l < CL; ++l) {
    const float* wq = Wqkv + (size_t)l * 3 * CD * CD;
    const float* bq = bqkv + (size_t)l * 3 * CD;
    gemm_kernel<0><<<gD, 256, 0, stream>>>(x, wq,                    bq,          qb, CS, CD, CD);
    gemm_kernel<0><<<gD, 256, 0, stream>>>(x, wq + (size_t)CD * CD,  bq + CD,     kb, CS, CD, CD);
    gemm_kernel<0><<<gD, 256, 0, stream>>>(x, wq + (size_t)2*CD*CD,  bq + 2 * CD, vb, CS, CD, CD);
    attn_kernel<<<dim3(CNC, CH), 256, 0, stream>>>(qb, kb, vb, mask, ctx);
    gemm_kernel<0><<<gD, 256, 0, stream>>>(ctx, Wo + (size_t)l * CD * CD, bo + (size_t)l * CD, t2, CS, CD, CD);
    add_ln_kernel<<<CS, 256, 0, stream>>>(t2, x, ln1s + (size_t)l * CD, ln1b + (size_t)l * CD);
    gemm_kernel<1><<<gF, 256, 0, stream>>>(x, W1 + (size_t)l * CD * CF, b1 + (size_t)l * CF, t1, CS, CF, CD);
    gemm_kernel<0><<<gD, 256, 0, stream>>>(t1, W2 + (size_t)l * CF * CD, b2 + (size_t)l * CD, t2, CS, CD, CF);
    add_ln_kernel<<<CS, 256, 0, stream>>>(t2, x, ln2s + (size_t)l * CD, ln2b + (size_t)l * CD);
  }

  finalize_kernel<<<(CS * CD) / 256, 256, 0, stream>>>(x, (float*)d_out);
  pool_kernel<<<1, 256, 0, stream>>>(x, poolW, poolb, (float*)d_out + SD);
}

// Round 3
// 1018.158 us; speedup vs baseline: 2.2919x; 2.2919x over previous
//
#include <hip/hip_runtime.h>
#include <hip/hip_bf16.h>
#include <math.h>
#include <stddef.h>
#include <stdint.h>

typedef __hip_bfloat16 bf16;
typedef short bf16x8 __attribute__((ext_vector_type(8)));
typedef float f32x4 __attribute__((ext_vector_type(4)));

#define CS 2048   // S
#define CD 768    // D
#define CH 12     // H
#define CDH 64    // DH
#define CF 3072   // F
#define CW 256    // W
#define CNC 8     // NC
#define CL 2      // L
#define QKVN 2304 // 3*D fused qkv width

// ---------------- async global->LDS, 16B per lane ----------------
__device__ __forceinline__ void gload_lds16(const bf16* g, bf16* l) {
  __builtin_amdgcn_global_load_lds(
      (const __attribute__((address_space(1))) void*)g,
      (__attribute__((address_space(3))) void*)l, 16, 0, 0);
}

// ---------------- block reduction (256 threads = 4 waves) ----------------
__device__ __forceinline__ float block_reduce_sum(float v, float* buf) {
  #pragma unroll
  for (int off = 32; off > 0; off >>= 1) v += __shfl_down(v, off, 64);
  int wid = threadIdx.x >> 6;
  __syncthreads();
  if ((threadIdx.x & 63) == 0) buf[wid] = v;
  __syncthreads();
  if (threadIdx.x == 0) buf[0] = buf[0] + buf[1] + buf[2] + buf[3];
  __syncthreads();
  return buf[0];
}

// ---------------- pos_ids = cumsum(mask)*mask + 1 ----------------
__global__ __launch_bounds__(256) void scan_kernel(const int* __restrict__ mask,
                                                   int* __restrict__ pos) {
  __shared__ int part[256];
  int tid = threadIdx.x;
  int mv[8]; int s = 0;
  #pragma unroll
  for (int i = 0; i < 8; ++i) { mv[i] = mask[tid * 8 + i]; s += mv[i]; }
  part[tid] = s;
  __syncthreads();
  for (int off = 1; off < 256; off <<= 1) {
    int t = 0;
    if (tid >= off) t = part[tid - off];
    __syncthreads();
    part[tid] += t;
    __syncthreads();
  }
  int run = part[tid] - s;
  #pragma unroll
  for (int i = 0; i < 8; ++i) {
    run += mv[i];
    pos[tid * 8 + i] = run * mv[i] + 1;
  }
}

// ---------------- weight transpose + fp32->bf16: out[n*K+k] = in[k*N+n] ----------------
// grid: (N/32, K/32, batch); block (32,8). batch stride = K*N for both.
__global__ __launch_bounds__(256) void transpose_conv(
    const float* __restrict__ in, bf16* __restrict__ out, int K, int N) {
  __shared__ float tile[32][33];
  int bn = blockIdx.x * 32, bk = blockIdx.y * 32;
  const float* src = in + (size_t)blockIdx.z * K * N;
  bf16* dst = out + (size_t)blockIdx.z * K * N;
  int tx = threadIdx.x, ty = threadIdx.y;
  #pragma unroll
  for (int i = 0; i < 32; i += 8)
    tile[ty + i][tx] = src[(size_t)(bk + ty + i) * N + bn + tx];
  __syncthreads();
  #pragma unroll
  for (int i = 0; i < 32; i += 8)
    dst[(size_t)(bn + ty + i) * K + bk + tx] = __float2bfloat16(tile[tx][ty + i]);
}

// ---------------- embedding gather + LN -> x (f32) + xb (bf16) ----------------
__global__ __launch_bounds__(256) void embed_ln_kernel(
    const int* __restrict__ ids, const int* __restrict__ pos,
    const float* __restrict__ wemb, const float* __restrict__ pemb,
    const float* __restrict__ temb, const float* __restrict__ gs,
    const float* __restrict__ gb, float* __restrict__ x, bf16* __restrict__ xb) {
  __shared__ float red[4];
  int srow = blockIdx.x;
  long long id = ids[srow];
  long long pid = pos[srow];
  float v[3];
  #pragma unroll
  for (int i = 0; i < 3; ++i) {
    int d = threadIdx.x + i * 256;
    v[i] = wemb[id * CD + d] + pemb[pid * CD + d] + temb[d];
  }
  float sum = v[0] + v[1] + v[2];
  sum = block_reduce_sum(sum, red);
  float mean = sum * (1.0f / CD);
  float sq = 0.f;
  #pragma unroll
  for (int i = 0; i < 3; ++i) { float c = v[i] - mean; sq += c * c; }
  sq = block_reduce_sum(sq, red);
  float rstd = rsqrtf(sq * (1.0f / CD) + 1e-5f);
  #pragma unroll
  for (int i = 0; i < 3; ++i) {
    int d = threadIdx.x + i * 256;
    float o = (v[i] - mean) * rstd * gs[d] + gb[d];
    x[(size_t)srow * CD + d] = o;
    xb[(size_t)srow * CD + d] = __float2bfloat16(o);
  }
}

// ---------------- MFMA GEMM: C = A(bf16 MxK) * Bt(bf16 NxK)^T + bias ----------------
// m97 structure: 128x128 tile, BK=32, 4 waves of 64x64 (4x4 16x16x32 tiles),
// global_load_lds width-16 staging. M%128==0, N%128==0, K%32==0 assumed.
template<int GELU, int OUTBF16>
__global__ __launch_bounds__(256) void gemm_mfma(
    const bf16* __restrict__ A, const bf16* __restrict__ Bt,
    const float* __restrict__ bias, void* __restrict__ Cout,
    int M, int N, int K) {
  __shared__ __align__(16) bf16 As[128 * 32];  // [row][k], rows of 64B
  __shared__ __align__(16) bf16 Bs[128 * 32];
  const int tid = threadIdx.x;
  const int wave = tid >> 6, lane = tid & 63;
  const int m0 = blockIdx.y * 128, n0 = blockIdx.x * 128;
  const int wm = (wave & 1) * 64, wn = (wave >> 1) * 64;
  const int quad = lane >> 4, rsel = lane & 15;
  // staging role: op = wave*4+i; ops 0-7 -> A rows op*16..+16, ops 8-15 -> B.
  // lane covers row op*16 + (lane>>2), 16B chunk (lane&3).
  const int r_in = lane >> 2;
  const int chunk = lane & 3;

  f32x4 acc[4][4] = {};

  for (int k0 = 0; k0 < K; k0 += 32) {
    #pragma unroll
    for (int i = 0; i < 4; ++i) {
      int op = wave * 4 + i;
      if (op < 8) {
        int row = op * 16 + r_in;
        gload_lds16(A + (size_t)(m0 + row) * K + k0 + chunk * 8, &As[op * 512]);
      } else {
        int row = (op - 8) * 16 + r_in;
        gload_lds16(Bt + (size_t)(n0 + row) * K + k0 + chunk * 8, &Bs[(op - 8) * 512]);
      }
    }
    __syncthreads();
    bf16x8 af[4], bfr[4];
    #pragma unroll
    for (int i = 0; i < 4; ++i)
      af[i] = *(const bf16x8*)&As[(wm + i * 16 + rsel) * 32 + quad * 8];
    #pragma unroll
    for (int j = 0; j < 4; ++j)
      bfr[j] = *(const bf16x8*)&Bs[(wn + j * 16 + rsel) * 32 + quad * 8];
    #pragma unroll
    for (int i = 0; i < 4; ++i)
      #pragma unroll
      for (int j = 0; j < 4; ++j)
        acc[i][j] = __builtin_amdgcn_mfma_f32_16x16x32_bf16(af[i], bfr[j], acc[i][j], 0, 0, 0);
    __syncthreads();
  }
  // epilogue: C/D layout col=lane&15, row=quad*4+reg
  #pragma unroll
  for (int j = 0; j < 4; ++j) {
    int col = n0 + wn + j * 16 + rsel;
    float bv = bias[col];
    #pragma unroll
    for (int i = 0; i < 4; ++i) {
      #pragma unroll
      for (int r = 0; r < 4; ++r) {
        int rowm = m0 + wm + i * 16 + quad * 4 + r;
        float v = acc[i][j][r] + bv;
        if (GELU) v = 0.5f * v * (1.0f + erff(v * 0.70710678118654752f));
        if (OUTBF16) ((bf16*)Cout)[(size_t)rowm * N + col] = __float2bfloat16(v);
        else         ((float*)Cout)[(size_t)rowm * N + col] = v;
      }
    }
  }
}

// ---------------- banded attention ----------------
// grid (S/64, H); block 256 = 64 queries x 4 parts (16 dims each).
// qkv fused (S, 2304) f32: q at +0, k at +768, v at +1536. Output ctx bf16 (S, D).
__global__ __launch_bounds__(256) void attn_kernel(
    const float* __restrict__ qkv, const int* __restrict__ mask,
    bf16* __restrict__ ctx) {
  __shared__ float Ks[64][64];
  __shared__ float Vs[64][64];
  __shared__ float vm[64];
  int h = blockIdx.y;
  int q0 = blockIdx.x * 64;
  int tid = threadIdx.x;
  int ql = tid >> 2;   // query within block
  int p  = tid & 3;    // dim part
  int qrow = q0 + ql;
  const float* qp = &qkv[(size_t)qrow * QKVN + h * CDH + p * 16];
  float qreg[16];
  #pragma unroll
  for (int d = 0; d < 16; d += 4) {
    float4 t = *(const float4*)&qp[d];
    qreg[d] = t.x; qreg[d+1] = t.y; qreg[d+2] = t.z; qreg[d+3] = t.w;
  }
  float m = -1e30f, l = 0.f;
  float o[16] = {};
  int pstart = q0 - CW;   // first key position covered by this block
  #pragma unroll 1
  for (int t0 = 0; t0 < 576; t0 += 64) {   // 64+2W = 576 keys
    __syncthreads();
    #pragma unroll 1
    for (int i = 0; i < 4; ++i) {
      int idx = i * 256 + tid;             // 0..1023 float4 slots
      int row = idx >> 4, col = (idx & 15) << 2;
      int pp = pstart + t0 + row;
      if (pp >= 0 && pp < CS) {
        *(float4*)&Ks[row][col] = *(const float4*)&qkv[(size_t)pp * QKVN + 768  + h * CDH + col];
        *(float4*)&Vs[row][col] = *(const float4*)&qkv[(size_t)pp * QKVN + 1536 + h * CDH + col];
      } else {
        float4 z = {0.f, 0.f, 0.f, 0.f};
        *(float4*)&Ks[row][col] = z;
        *(float4*)&Vs[row][col] = z;
      }
    }
    if (tid < 64) {
      int pp = pstart + t0 + tid;
      vm[tid] = (pp >= 0 && pp < CS && mask[pp] != 0) ? 1.f : 0.f;
    }
    __syncthreads();
    #pragma unroll 1
    for (int jj = 0; jj < 64; ++jj) {
      int pp = pstart + t0 + jj;
      const float4* krow = (const float4*)&Ks[jj][p * 16];
      float dp = 0.f;
      #pragma unroll
      for (int dd = 0; dd < 4; ++dd) {
        float4 kv = krow[dd];
        dp = fmaf(qreg[4*dd+0], kv.x, dp);
        dp = fmaf(qreg[4*dd+1], kv.y, dp);
        dp = fmaf(qreg[4*dd+2], kv.z, dp);
        dp = fmaf(qreg[4*dd+3], kv.w, dp);
      }
      dp += __shfl_xor(dp, 1, 64);
      dp += __shfl_xor(dp, 2, 64);
      bool band = (pp >= qrow - CW) && (pp <= qrow + CW);
      float s = (band && vm[jj] > 0.5f) ? dp * 0.125f : -1e9f;
      if (s > m) {
        float fac = __expf(m - s);
        l *= fac;
        #pragma unroll
        for (int d = 0; d < 16; ++d) o[d] *= fac;
        m = s;
      }
      float pr = __expf(s - m);
      l += pr;
      const float4* vrow = (const float4*)&Vs[jj][p * 16];
      #pragma unroll
      for (int dd = 0; dd < 4; ++dd) {
        float4 vv = vrow[dd];
        o[4*dd+0] = fmaf(pr, vv.x, o[4*dd+0]);
        o[4*dd+1] = fmaf(pr, vv.y, o[4*dd+1]);
        o[4*dd+2] = fmaf(pr, vv.z, o[4*dd+2]);
        o[4*dd+3] = fmaf(pr, vv.w, o[4*dd+3]);
      }
    }
  }
  float inv = 1.0f / l;
  bf16* op = &ctx[(size_t)qrow * CD + h * CDH + p * 16];
  #pragma unroll
  for (int d = 0; d < 16; ++d) op[d] = __float2bfloat16(o[d] * inv);
}

// ---------------- x = LN(x + g); also writes xb (bf16) ----------------
__global__ __launch_bounds__(256) void add_ln_kernel(
    const float* __restrict__ g, float* __restrict__ x, bf16* __restrict__ xb,
    const float* __restrict__ gs, const float* __restrict__ gb) {
  __shared__ float red[4];
  int srow = blockIdx.x;
  float v[3];
  #pragma unroll
  for (int i = 0; i < 3; ++i) {
    int d = threadIdx.x + i * 256;
    v[i] = g[(size_t)srow * CD + d] + x[(size_t)srow * CD + d];
  }
  float sum = v[0] + v[1] + v[2];
  sum = block_reduce_sum(sum, red);
  float mean = sum * (1.0f / CD);
  float sq = 0.f;
  #pragma unroll
  for (int i = 0; i < 3; ++i) { float c = v[i] - mean; sq += c * c; }
  sq = block_reduce_sum(sq, red);
  float rstd = rsqrtf(sq * (1.0f / CD) + 1e-5f);
  #pragma unroll
  for (int i = 0; i < 3; ++i) {
    int d = threadIdx.x + i * 256;
    float o = (v[i] - mean) * rstd * gs[d] + gb[d];
    x[(size_t)srow * CD + d] = o;
    xb[(size_t)srow * CD + d] = __float2bfloat16(o);
  }
}

// ---------------- x (f32) -> out (f32) ----------------
__global__ __launch_bounds__(256) void finalize_kernel(const float* __restrict__ x,
                                                       float* __restrict__ out) {
  int i = blockIdx.x * 256 + threadIdx.x;
  out[i] = x[i];
}

// ---------------- pooled = tanh(x[0] @ pool_W + pool_b) ----------------
__global__ __launch_bounds__(256) void pool_kernel(
    const float* __restrict__ x, const float* __restrict__ Wp,
    const float* __restrict__ bp, float* __restrict__ out) {
  __shared__ float xs[CD];
  for (int i = threadIdx.x; i < CD; i += 256) xs[i] = x[i];
  __syncthreads();
  for (int n = threadIdx.x; n < CD; n += 256) {
    float acc = bp[n];
    for (int kk = 0; kk < CD; ++kk) acc = fmaf(xs[kk], Wp[(size_t)kk * CD + n], acc);
    out[n] = tanhf(acc);
  }
}

extern "C" void kernel_launch(void* const* d_in, const int* in_sizes, int n_in,
                              void* d_out, int out_size, void* d_ws, size_t ws_size,
                              hipStream_t stream) {
  const int*   ids   = (const int*)d_in[0];
  const int*   mask  = (const int*)d_in[1];
  const float* wemb  = (const float*)d_in[2];
  const float* pemb  = (const float*)d_in[3];
  const float* temb  = (const float*)d_in[4];
  const float* elns  = (const float*)d_in[5];
  const float* elnb  = (const float*)d_in[6];
  const float* Wqkv  = (const float*)d_in[7];
  const float* bqkv  = (const float*)d_in[8];
  const float* Wo    = (const float*)d_in[9];
  const float* bo    = (const float*)d_in[10];
  const float* ln1s  = (const float*)d_in[11];
  const float* ln1b  = (const float*)d_in[12];
  const float* W1    = (const float*)d_in[13];
  const float* b1    = (const float*)d_in[14];
  const float* W2    = (const float*)d_in[15];
  const float* b2    = (const float*)d_in[16];
  const float* ln2s  = (const float*)d_in[17];
  const float* ln2b  = (const float*)d_in[18];
  const float* poolW = (const float*)d_in[19];
  const float* poolb = (const float*)d_in[20];

  const size_t SD = (size_t)CS * CD;
  const size_t SF = (size_t)CS * CF;

  char* w = (char*)d_ws;
  float* x    = (float*)w; w += SD * 4;
  bf16*  xb   = (bf16*)w;  w += SD * 2;
  float* qkv  = (float*)w; w += (size_t)CS * QKVN * 4;
  bf16*  ctxb = (bf16*)w;  w += SD * 2;
  bf16*  t1b  = (bf16*)w;  w += SF * 2;
  float* t2   = (float*)w; w += SD * 4;
  int*   pos  = (int*)w;   w += (size_t)CS * 4;
  bf16* WqkvT = (bf16*)w;  w += (size_t)CL * QKVN * CD * 2;
  bf16* WoT   = (bf16*)w;  w += (size_t)CL * CD * CD * 2;
  bf16* W1T   = (bf16*)w;  w += (size_t)CL * CF * CD * 2;
  bf16* W2T   = (bf16*)w;  w += (size_t)CL * CD * CF * 2;

  dim3 tb(32, 8);
  scan_kernel<<<1, 256, 0, stream>>>(mask, pos);
  // weight prep (batched over layers via grid.z; batch stride K*N)
  transpose_conv<<<dim3(CD/32, CD/32, CL*3), tb, 0, stream>>>(Wqkv, WqkvT, CD, CD);
  transpose_conv<<<dim3(CD/32, CD/32, CL),   tb, 0, stream>>>(Wo,   WoT,   CD, CD);
  transpose_conv<<<dim3(CF/32, CD/32, CL),   tb, 0, stream>>>(W1,   W1T,   CD, CF);
  transpose_conv<<<dim3(CD/32, CF/32, CL),   tb, 0, stream>>>(W2,   W2T,   CF, CD);
  embed_ln_kernel<<<CS, 256, 0, stream>>>(ids, pos, wemb, pemb, temb, elns, elnb, x, xb);

  for (int l = 0; l < CL; ++l) {
    gemm_mfma<0,0><<<dim3(QKVN/128, CS/128), 256, 0, stream>>>(
        xb, WqkvT + (size_t)l * QKVN * CD, bqkv + (size_t)l * 3 * CD, qkv, CS, QKVN, CD);
    attn_kernel<<<dim3(CS/64, CH), 256, 0, stream>>>(qkv, mask, ctxb);
    gemm_mfma<0,0><<<dim3(CD/128, CS/128), 256, 0, stream>>>(
        ctxb, WoT + (size_t)l * CD * CD, bo + (size_t)l * CD, t2, CS, CD, CD);
    add_ln_kernel<<<CS, 256, 0, stream>>>(t2, x, xb, ln1s + (size_t)l * CD, ln1b + (size_t)l * CD);
    gemm_mfma<1,1><<<dim3(CF/128, CS/128), 256, 0, stream>>>(
        xb, W1T + (size_t)l * CF * CD, b1 + (size_t)l * CF, t1b, CS, CF, CD);
    gemm_mfma<0,0><<<dim3(CD/128, CS/128), 256, 0, stream>>>(
        t1b, W2T + (size_t)l * CD * CF, b2 + (size_t)l * CD, t2, CS, CD, CF);
    add_ln_kernel<<<CS, 256, 0, stream>>>(t2, x, xb, ln2s + (size_t)l * CD, ln2b + (size_t)l * CD);
  }

  finalize_kernel<<<(CS * CD) / 256, 256, 0, stream>>>(x, (float*)d_out);
  pool_kernel<<<1, 256, 0, stream>>>(x, poolW, poolb, (float*)d_out + SD);
}

// Round 4
// 651.563 us; speedup vs baseline: 3.5814x; 1.5626x over previous
//
#include <hip/hip_runtime.h>
#include <hip/hip_bf16.h>
#include <math.h>
#include <stddef.h>
#include <stdint.h>

typedef __hip_bfloat16 bf16;
typedef short bf16x8 __attribute__((ext_vector_type(8)));
typedef float f32x4 __attribute__((ext_vector_type(4)));

#define CS 2048   // S
#define CD 768    // D
#define CH 12     // H
#define CDH 64    // DH
#define CF 3072   // F
#define CW 256    // W
#define CL 2      // L
#define QKVN 2304 // 3*D fused qkv width

// ---------------- async global->LDS, 16B per lane ----------------
__device__ __forceinline__ void gload_lds16(const bf16* g, bf16* l) {
  __builtin_amdgcn_global_load_lds(
      (const __attribute__((address_space(1))) void*)g,
      (__attribute__((address_space(3))) void*)l, 16, 0, 0);
}

// ---------------- block reduction (256 threads = 4 waves) ----------------
__device__ __forceinline__ float block_reduce_sum(float v, float* buf) {
  #pragma unroll
  for (int off = 32; off > 0; off >>= 1) v += __shfl_down(v, off, 64);
  int wid = threadIdx.x >> 6;
  __syncthreads();
  if ((threadIdx.x & 63) == 0) buf[wid] = v;
  __syncthreads();
  if (threadIdx.x == 0) buf[0] = buf[0] + buf[1] + buf[2] + buf[3];
  __syncthreads();
  return buf[0];
}

// ---------------- pos_ids = cumsum(mask)*mask + 1 ----------------
__global__ __launch_bounds__(256) void scan_kernel(const int* __restrict__ mask,
                                                   int* __restrict__ pos) {
  __shared__ int part[256];
  int tid = threadIdx.x;
  int mv[8]; int s = 0;
  #pragma unroll
  for (int i = 0; i < 8; ++i) { mv[i] = mask[tid * 8 + i]; s += mv[i]; }
  part[tid] = s;
  __syncthreads();
  for (int off = 1; off < 256; off <<= 1) {
    int t = 0;
    if (tid >= off) t = part[tid - off];
    __syncthreads();
    part[tid] += t;
    __syncthreads();
  }
  int run = part[tid] - s;
  #pragma unroll
  for (int i = 0; i < 8; ++i) {
    run += mv[i];
    pos[tid * 8 + i] = run * mv[i] + 1;
  }
}

// ---------------- weight transpose + fp32->bf16: out[n*K+k] = in[k*N+n] ----------------
__global__ __launch_bounds__(256) void transpose_conv(
    const float* __restrict__ in, bf16* __restrict__ out, int K, int N) {
  __shared__ float tile[32][33];
  int bn = blockIdx.x * 32, bk = blockIdx.y * 32;
  const float* src = in + (size_t)blockIdx.z * K * N;
  bf16* dst = out + (size_t)blockIdx.z * K * N;
  int tx = threadIdx.x, ty = threadIdx.y;
  #pragma unroll
  for (int i = 0; i < 32; i += 8)
    tile[ty + i][tx] = src[(size_t)(bk + ty + i) * N + bn + tx];
  __syncthreads();
  #pragma unroll
  for (int i = 0; i < 32; i += 8)
    dst[(size_t)(bn + ty + i) * K + bk + tx] = __float2bfloat16(tile[tx][ty + i]);
}

// ---------------- embedding gather + LN -> x (f32) + xb (bf16) ----------------
__global__ __launch_bounds__(256) void embed_ln_kernel(
    const int* __restrict__ ids, const int* __restrict__ pos,
    const float* __restrict__ wemb, const float* __restrict__ pemb,
    const float* __restrict__ temb, const float* __restrict__ gs,
    const float* __restrict__ gb, float* __restrict__ x, bf16* __restrict__ xb) {
  __shared__ float red[4];
  int srow = blockIdx.x;
  long long id = ids[srow];
  long long pid = pos[srow];
  float v[3];
  #pragma unroll
  for (int i = 0; i < 3; ++i) {
    int d = threadIdx.x + i * 256;
    v[i] = wemb[id * CD + d] + pemb[pid * CD + d] + temb[d];
  }
  float sum = v[0] + v[1] + v[2];
  sum = block_reduce_sum(sum, red);
  float mean = sum * (1.0f / CD);
  float sq = 0.f;
  #pragma unroll
  for (int i = 0; i < 3; ++i) { float c = v[i] - mean; sq += c * c; }
  sq = block_reduce_sum(sq, red);
  float rstd = rsqrtf(sq * (1.0f / CD) + 1e-5f);
  #pragma unroll
  for (int i = 0; i < 3; ++i) {
    int d = threadIdx.x + i * 256;
    float o = (v[i] - mean) * rstd * gs[d] + gb[d];
    x[(size_t)srow * CD + d] = o;
    xb[(size_t)srow * CD + d] = __float2bfloat16(o);
  }
}

// ---------------- MFMA GEMM: C = A(bf16 MxK) * Bt(bf16 NxK)^T + bias ----------------
template<int GELU, int OUTBF16>
__global__ __launch_bounds__(256) void gemm_mfma(
    const bf16* __restrict__ A, const bf16* __restrict__ Bt,
    const float* __restrict__ bias, void* __restrict__ Cout,
    int M, int N, int K) {
  __shared__ __align__(16) bf16 As[128 * 32];
  __shared__ __align__(16) bf16 Bs[128 * 32];
  const int tid = threadIdx.x;
  const int wave = tid >> 6, lane = tid & 63;
  const int m0 = blockIdx.y * 128, n0 = blockIdx.x * 128;
  const int wm = (wave & 1) * 64, wn = (wave >> 1) * 64;
  const int quad = lane >> 4, rsel = lane & 15;
  const int r_in = lane >> 2;
  const int chunk = lane & 3;

  f32x4 acc[4][4] = {};

  for (int k0 = 0; k0 < K; k0 += 32) {
    #pragma unroll
    for (int i = 0; i < 4; ++i) {
      int op = wave * 4 + i;
      if (op < 8) {
        int row = op * 16 + r_in;
        gload_lds16(A + (size_t)(m0 + row) * K + k0 + chunk * 8, &As[op * 512]);
      } else {
        int row = (op - 8) * 16 + r_in;
        gload_lds16(Bt + (size_t)(n0 + row) * K + k0 + chunk * 8, &Bs[(op - 8) * 512]);
      }
    }
    __syncthreads();
    bf16x8 af[4], bfr[4];
    #pragma unroll
    for (int i = 0; i < 4; ++i)
      af[i] = *(const bf16x8*)&As[(wm + i * 16 + rsel) * 32 + quad * 8];
    #pragma unroll
    for (int j = 0; j < 4; ++j)
      bfr[j] = *(const bf16x8*)&Bs[(wn + j * 16 + rsel) * 32 + quad * 8];
    #pragma unroll
    for (int i = 0; i < 4; ++i)
      #pragma unroll
      for (int j = 0; j < 4; ++j)
        acc[i][j] = __builtin_amdgcn_mfma_f32_16x16x32_bf16(af[i], bfr[j], acc[i][j], 0, 0, 0);
    __syncthreads();
  }
  #pragma unroll
  for (int j = 0; j < 4; ++j) {
    int col = n0 + wn + j * 16 + rsel;
    float bv = bias[col];
    #pragma unroll
    for (int i = 0; i < 4; ++i) {
      #pragma unroll
      for (int r = 0; r < 4; ++r) {
        int rowm = m0 + wm + i * 16 + quad * 4 + r;
        float v = acc[i][j][r] + bv;
        if (GELU) v = 0.5f * v * (1.0f + erff(v * 0.70710678118654752f));
        if (OUTBF16) ((bf16*)Cout)[(size_t)rowm * N + col] = __float2bfloat16(v);
        else         ((float*)Cout)[(size_t)rowm * N + col] = v;
      }
    }
  }
}

// ---------------- MFMA flash attention (banded) ----------------
// grid (S/64, H); block 256 = 4 waves; wave w owns queries q0+w*16..+15.
// qkv is bf16 (S, 2304): Q +0, K +768, V +1536 (per head +h*64).
// Per 64-key tile: stage K[key][dh] and Vt[dh][key] (bf16, stride 72) in LDS;
// QK^T mfma -> online softmax (C layout) -> P via LDS -> PV mfma.
__global__ __launch_bounds__(256) void attn_mfma(
    const bf16* __restrict__ qkv, const int* __restrict__ mask,
    bf16* __restrict__ ctx) {
  __shared__ bf16 Ks[64][72];
  __shared__ bf16 Vt[64][72];
  __shared__ bf16 Ps[4][16][72];
  __shared__ float vmf[64];
  const int h = blockIdx.y;
  const int q0 = blockIdx.x * 64;
  const int tid = threadIdx.x;
  const int wv = tid >> 6, lane = tid & 63;
  const int quad = lane >> 4, rsel = lane & 15;
  const int qw = q0 + wv * 16;          // wave's first query row
  const int pstart = q0 - CW;           // first key pos covered by block

  // Q fragments (A-operand): row = qw+rsel, k = quad*8.. (+32 for second k-step)
  const bf16* qp = &qkv[(size_t)(qw + rsel) * QKVN + h * CDH + quad * 8];
  bf16x8 qf0 = *(const bf16x8*)qp;
  bf16x8 qf1 = *(const bf16x8*)(qp + 32);

  float mi[4], li[4];
  f32x4 o[4] = {};
  #pragma unroll
  for (int r = 0; r < 4; ++r) { mi[r] = -1e30f; li[r] = 0.f; }

  const int skey = tid >> 2;            // staging: key row 0..63
  const int sdq  = (tid & 3) * 16;      // staging: dh chunk

  #pragma unroll 1
  for (int kt = 0; kt < 9; ++kt) {
    int kbase = pstart + kt * 64;
    if (kbase + 63 < 0 || kbase >= CS) continue;
    __syncthreads();
    {
      int pp = kbase + skey;
      if (pp >= 0 && pp < CS) {
        const bf16* kp = &qkv[(size_t)pp * QKVN + 768 + h * CDH + sdq];
        const bf16* vp = &qkv[(size_t)pp * QKVN + 1536 + h * CDH + sdq];
        bf16x8 k0 = *(const bf16x8*)kp, k1 = *(const bf16x8*)(kp + 8);
        bf16x8 v0 = *(const bf16x8*)vp, v1 = *(const bf16x8*)(vp + 8);
        *(bf16x8*)&Ks[skey][sdq] = k0;
        *(bf16x8*)&Ks[skey][sdq + 8] = k1;
        #pragma unroll
        for (int i = 0; i < 8; ++i) {
          Vt[sdq + i][skey] = ((bf16*)&v0)[i] ? *(bf16*)&((short*)&v0)[i] : *(bf16*)&((short*)&v0)[i];
        }
        #pragma unroll
        for (int i = 0; i < 8; ++i) Vt[sdq + 8 + i][skey] = *(bf16*)&((short*)&v1)[i];
      } else {
        bf16 z = __float2bfloat16(0.f);
        bf16x8 zv = {};
        *(bf16x8*)&Ks[skey][sdq] = zv;
        *(bf16x8*)&Ks[skey][sdq + 8] = zv;
        #pragma unroll
        for (int i = 0; i < 16; ++i) Vt[sdq + i][skey] = z;
      }
      if (tid < 64) {
        int p2 = kbase + tid;
        vmf[tid] = (p2 >= 0 && p2 < CS && mask[p2] != 0) ? 1.f : 0.f;
      }
    }
    __syncthreads();

    // ---- QK^T: scores for 16 queries x 64 keys ----
    f32x4 sc[4];
    #pragma unroll
    for (int nt = 0; nt < 4; ++nt) {
      bf16x8 kf0 = *(const bf16x8*)&Ks[nt * 16 + rsel][quad * 8];
      bf16x8 kf1 = *(const bf16x8*)&Ks[nt * 16 + rsel][32 + quad * 8];
      f32x4 z = {};
      z = __builtin_amdgcn_mfma_f32_16x16x32_bf16(qf0, kf0, z, 0, 0, 0);
      z = __builtin_amdgcn_mfma_f32_16x16x32_bf16(qf1, kf1, z, 0, 0, 0);
      sc[nt] = z;
    }
    // ---- mask + scale; row-wise max ----
    float mx[4] = {-1e30f, -1e30f, -1e30f, -1e30f};
    #pragma unroll
    for (int nt = 0; nt < 4; ++nt) {
      int pp = kbase + nt * 16 + rsel;
      bool kvld = vmf[nt * 16 + rsel] > 0.5f;
      #pragma unroll
      for (int r = 0; r < 4; ++r) {
        int qr = qw + quad * 4 + r;
        float s = sc[nt][r] * 0.125f;
        bool band = (pp >= qr - CW) && (pp <= qr + CW);
        s = (kvld && band) ? s : -1e9f;
        sc[nt][r] = s;
        mx[r] = fmaxf(mx[r], s);
      }
    }
    #pragma unroll
    for (int r = 0; r < 4; ++r) {
      #pragma unroll
      for (int off = 1; off < 16; off <<= 1)
        mx[r] = fmaxf(mx[r], __shfl_xor(mx[r], off, 64));
    }
    float al[4], rs[4] = {};
    #pragma unroll
    for (int r = 0; r < 4; ++r) {
      float mn = fmaxf(mi[r], mx[r]);
      al[r] = __expf(mi[r] - mn);
      mi[r] = mn;
    }
    #pragma unroll
    for (int nt = 0; nt < 4; ++nt)
      #pragma unroll
      for (int r = 0; r < 4; ++r) {
        float p = __expf(sc[nt][r] - mi[r]);
        sc[nt][r] = p;
        rs[r] += p;
      }
    #pragma unroll
    for (int r = 0; r < 4; ++r) {
      #pragma unroll
      for (int off = 1; off < 16; off <<= 1)
        rs[r] += __shfl_xor(rs[r], off, 64);
      li[r] = li[r] * al[r] + rs[r];
    }
    #pragma unroll
    for (int d = 0; d < 4; ++d)
      #pragma unroll
      for (int r = 0; r < 4; ++r) o[d][r] *= al[r];
    // ---- P -> LDS (C layout -> A layout round trip) ----
    #pragma unroll
    for (int nt = 0; nt < 4; ++nt)
      #pragma unroll
      for (int r = 0; r < 4; ++r)
        Ps[wv][quad * 4 + r][nt * 16 + rsel] = __float2bfloat16(sc[nt][r]);
    __asm__ volatile("s_waitcnt lgkmcnt(0)" ::: "memory");
    bf16x8 pf0 = *(const bf16x8*)&Ps[wv][rsel][quad * 8];
    bf16x8 pf1 = *(const bf16x8*)&Ps[wv][rsel][32 + quad * 8];
    #pragma unroll
    for (int d = 0; d < 4; ++d) {
      bf16x8 vf0 = *(const bf16x8*)&Vt[d * 16 + rsel][quad * 8];
      bf16x8 vf1 = *(const bf16x8*)&Vt[d * 16 + rsel][32 + quad * 8];
      o[d] = __builtin_amdgcn_mfma_f32_16x16x32_bf16(pf0, vf0, o[d], 0, 0, 0);
      o[d] = __builtin_amdgcn_mfma_f32_16x16x32_bf16(pf1, vf1, o[d], 0, 0, 0);
    }
  }
  // ---- write ctx: row = qw+quad*4+r, col(dh) = d*16+rsel ----
  float inv[4];
  #pragma unroll
  for (int r = 0; r < 4; ++r) inv[r] = 1.0f / li[r];
  #pragma unroll
  for (int d = 0; d < 4; ++d)
    #pragma unroll
    for (int r = 0; r < 4; ++r)
      ctx[(size_t)(qw + quad * 4 + r) * CD + h * CDH + d * 16 + rsel] =
          __float2bfloat16(o[d][r] * inv[r]);
}

// ---------------- xout = LN(xin + g); also writes xb (bf16) ----------------
__global__ __launch_bounds__(256) void add_ln_kernel(
    const float* __restrict__ g, const float* __restrict__ xin,
    float* __restrict__ xout, bf16* __restrict__ xb,
    const float* __restrict__ gs, const float* __restrict__ gb) {
  __shared__ float red[4];
  int srow = blockIdx.x;
  float v[3];
  #pragma unroll
  for (int i = 0; i < 3; ++i) {
    int d = threadIdx.x + i * 256;
    v[i] = g[(size_t)srow * CD + d] + xin[(size_t)srow * CD + d];
  }
  float sum = v[0] + v[1] + v[2];
  sum = block_reduce_sum(sum, red);
  float mean = sum * (1.0f / CD);
  float sq = 0.f;
  #pragma unroll
  for (int i = 0; i < 3; ++i) { float c = v[i] - mean; sq += c * c; }
  sq = block_reduce_sum(sq, red);
  float rstd = rsqrtf(sq * (1.0f / CD) + 1e-5f);
  #pragma unroll
  for (int i = 0; i < 3; ++i) {
    int d = threadIdx.x + i * 256;
    float o = (v[i] - mean) * rstd * gs[d] + gb[d];
    xout[(size_t)srow * CD + d] = o;
    xb[(size_t)srow * CD + d] = __float2bfloat16(o);
  }
}

// ---------------- pooled = tanh(x[0] @ pool_W + pool_b) ----------------
// grid 12 blocks; block b handles outputs b*64..+63; 4-way K split.
__global__ __launch_bounds__(256) void pool_kernel(
    const float* __restrict__ x, const float* __restrict__ Wp,
    const float* __restrict__ bp, float* __restrict__ out) {
  __shared__ float xs[CD];
  __shared__ float red[4][64];
  int t = threadIdx.x;
  for (int i = t; i < CD; i += 256) xs[i] = x[i];
  __syncthreads();
  int n = blockIdx.x * 64 + (t & 63);
  int kp = t >> 6;
  float acc = 0.f;
  #pragma unroll 4
  for (int kk = kp * 192; kk < kp * 192 + 192; ++kk)
    acc = fmaf(xs[kk], Wp[(size_t)kk * CD + n], acc);
  red[kp][t & 63] = acc;
  __syncthreads();
  if (t < 64) {
    int nn = blockIdx.x * 64 + t;
    out[nn] = tanhf(red[0][t] + red[1][t] + red[2][t] + red[3][t] + bp[nn]);
  }
}

extern "C" void kernel_launch(void* const* d_in, const int* in_sizes, int n_in,
                              void* d_out, int out_size, void* d_ws, size_t ws_size,
                              hipStream_t stream) {
  const int*   ids   = (const int*)d_in[0];
  const int*   mask  = (const int*)d_in[1];
  const float* wemb  = (const float*)d_in[2];
  const float* pemb  = (const float*)d_in[3];
  const float* temb  = (const float*)d_in[4];
  const float* elns  = (const float*)d_in[5];
  const float* elnb  = (const float*)d_in[6];
  const float* Wqkv  = (const float*)d_in[7];
  const float* bqkv  = (const float*)d_in[8];
  const float* Wo    = (const float*)d_in[9];
  const float* bo    = (const float*)d_in[10];
  const float* ln1s  = (const float*)d_in[11];
  const float* ln1b  = (const float*)d_in[12];
  const float* W1    = (const float*)d_in[13];
  const float* b1    = (const float*)d_in[14];
  const float* W2    = (const float*)d_in[15];
  const float* b2    = (const float*)d_in[16];
  const float* ln2s  = (const float*)d_in[17];
  const float* ln2b  = (const float*)d_in[18];
  const float* poolW = (const float*)d_in[19];
  const float* poolb = (const float*)d_in[20];

  const size_t SD = (size_t)CS * CD;
  const size_t SF = (size_t)CS * CF;

  char* w = (char*)d_ws;
  float* x    = (float*)w; w += SD * 4;
  bf16*  xb   = (bf16*)w;  w += SD * 2;
  bf16*  qkv  = (bf16*)w;  w += (size_t)CS * QKVN * 2;
  bf16*  ctxb = (bf16*)w;  w += SD * 2;
  bf16*  t1b  = (bf16*)w;  w += SF * 2;
  float* t2   = (float*)w; w += SD * 4;
  int*   pos  = (int*)w;   w += (size_t)CS * 4;
  bf16* WqkvT = (bf16*)w;  w += (size_t)CL * QKVN * CD * 2;
  bf16* WoT   = (bf16*)w;  w += (size_t)CL * CD * CD * 2;
  bf16* W1T   = (bf16*)w;  w += (size_t)CL * CF * CD * 2;
  bf16* W2T   = (bf16*)w;  w += (size_t)CL * CD * CF * 2;

  dim3 tb(32, 8);
  scan_kernel<<<1, 256, 0, stream>>>(mask, pos);
  transpose_conv<<<dim3(CD/32, CD/32, CL*3), tb, 0, stream>>>(Wqkv, WqkvT, CD, CD);
  transpose_conv<<<dim3(CD/32, CD/32, CL),   tb, 0, stream>>>(Wo,   WoT,   CD, CD);
  transpose_conv<<<dim3(CF/32, CD/32, CL),   tb, 0, stream>>>(W1,   W1T,   CD, CF);
  transpose_conv<<<dim3(CD/32, CF/32, CL),   tb, 0, stream>>>(W2,   W2T,   CF, CD);
  embed_ln_kernel<<<CS, 256, 0, stream>>>(ids, pos, wemb, pemb, temb, elns, elnb, x, xb);

  for (int l = 0; l < CL; ++l) {
    gemm_mfma<0,1><<<dim3(QKVN/128, CS/128), 256, 0, stream>>>(
        xb, WqkvT + (size_t)l * QKVN * CD, bqkv + (size_t)l * 3 * CD, qkv, CS, QKVN, CD);
    attn_mfma<<<dim3(CS/64, CH), 256, 0, stream>>>(qkv, mask, ctxb);
    gemm_mfma<0,0><<<dim3(CD/128, CS/128), 256, 0, stream>>>(
        ctxb, WoT + (size_t)l * CD * CD, bo + (size_t)l * CD, t2, CS, CD, CD);
    add_ln_kernel<<<CS, 256, 0, stream>>>(t2, x, x, xb,
        ln1s + (size_t)l * CD, ln1b + (size_t)l * CD);
    gemm_mfma<1,1><<<dim3(CF/128, CS/128), 256, 0, stream>>>(
        xb, W1T + (size_t)l * CF * CD, b1 + (size_t)l * CF, t1b, CS, CF, CD);
    gemm_mfma<0,0><<<dim3(CD/128, CS/128), 256, 0, stream>>>(
        t1b, W2T + (size_t)l * CD * CF, b2 + (size_t)l * CD, t2, CS, CD, CF);
    float* lastx = (l == CL - 1) ? (float*)d_out : x;
    add_ln_kernel<<<CS, 256, 0, stream>>>(t2, x, lastx, xb,
        ln2s + (size_t)l * CD, ln2b + (size_t)l * CD);
  }

  pool_kernel<<<12, 256, 0, stream>>>((float*)d_out, poolW, poolb, (float*)d_out + SD);
}

// Round 5
// 616.964 us; speedup vs baseline: 3.7823x; 1.0561x over previous
//
#include <hip/hip_runtime.h>
#include <hip/hip_bf16.h>
#include <math.h>
#include <stddef.h>
#include <stdint.h>

typedef __hip_bfloat16 bf16;
typedef short bf16x8 __attribute__((ext_vector_type(8)));
typedef float f32x4 __attribute__((ext_vector_type(4)));

#define CS 2048   // S
#define CD 768    // D
#define CH 12     // H
#define CDH 64    // DH
#define CF 3072   // F
#define CW 256    // W
#define CL 2      // L
#define QKVN 2304 // 3*D fused qkv width
#define SDC ((size_t)CS * CD)

// ---------------- async global->LDS, 16B per lane ----------------
__device__ __forceinline__ void gload_lds16(const bf16* g, bf16* l) {
  __builtin_amdgcn_global_load_lds(
      (const __attribute__((address_space(1))) void*)g,
      (__attribute__((address_space(3))) void*)l, 16, 0, 0);
}

// ---------------- block reduction (256 threads = 4 waves) ----------------
__device__ __forceinline__ float block_reduce_sum(float v, float* buf) {
  #pragma unroll
  for (int off = 32; off > 0; off >>= 1) v += __shfl_down(v, off, 64);
  int wid = threadIdx.x >> 6;
  __syncthreads();
  if ((threadIdx.x & 63) == 0) buf[wid] = v;
  __syncthreads();
  if (threadIdx.x == 0) buf[0] = buf[0] + buf[1] + buf[2] + buf[3];
  __syncthreads();
  return buf[0];
}

// ---------------- pos_ids = cumsum(mask)*mask + 1 ----------------
__global__ __launch_bounds__(256) void scan_kernel(const int* __restrict__ mask,
                                                   int* __restrict__ pos) {
  __shared__ int part[256];
  int tid = threadIdx.x;
  int mv[8]; int s = 0;
  #pragma unroll
  for (int i = 0; i < 8; ++i) { mv[i] = mask[tid * 8 + i]; s += mv[i]; }
  part[tid] = s;
  __syncthreads();
  for (int off = 1; off < 256; off <<= 1) {
    int t = 0;
    if (tid >= off) t = part[tid - off];
    __syncthreads();
    part[tid] += t;
    __syncthreads();
  }
  int run = part[tid] - s;
  #pragma unroll
  for (int i = 0; i < 8; ++i) {
    run += mv[i];
    pos[tid * 8 + i] = run * mv[i] + 1;
  }
}

// ---------------- weight transpose + fp32->bf16: out[n*K+k] = in[k*N+n] ----------------
__global__ __launch_bounds__(256) void transpose_conv(
    const float* __restrict__ in, bf16* __restrict__ out, int K, int N) {
  __shared__ float tile[32][33];
  int bn = blockIdx.x * 32, bk = blockIdx.y * 32;
  const float* src = in + (size_t)blockIdx.z * K * N;
  bf16* dst = out + (size_t)blockIdx.z * K * N;
  int tx = threadIdx.x, ty = threadIdx.y;
  #pragma unroll
  for (int i = 0; i < 32; i += 8)
    tile[ty + i][tx] = src[(size_t)(bk + ty + i) * N + bn + tx];
  __syncthreads();
  #pragma unroll
  for (int i = 0; i < 32; i += 8)
    dst[(size_t)(bn + ty + i) * K + bk + tx] = __float2bfloat16(tile[tx][ty + i]);
}

// ---------------- embedding gather + LN -> x (f32) + xb (bf16) ----------------
__global__ __launch_bounds__(256) void embed_ln_kernel(
    const int* __restrict__ ids, const int* __restrict__ pos,
    const float* __restrict__ wemb, const float* __restrict__ pemb,
    const float* __restrict__ temb, const float* __restrict__ gs,
    const float* __restrict__ gb, float* __restrict__ x, bf16* __restrict__ xb) {
  __shared__ float red[4];
  int srow = blockIdx.x;
  long long id = ids[srow];
  long long pid = pos[srow];
  float v[3];
  #pragma unroll
  for (int i = 0; i < 3; ++i) {
    int d = threadIdx.x + i * 256;
    v[i] = wemb[id * CD + d] + pemb[pid * CD + d] + temb[d];
  }
  float sum = v[0] + v[1] + v[2];
  sum = block_reduce_sum(sum, red);
  float mean = sum * (1.0f / CD);
  float sq = 0.f;
  #pragma unroll
  for (int i = 0; i < 3; ++i) { float c = v[i] - mean; sq += c * c; }
  sq = block_reduce_sum(sq, red);
  float rstd = rsqrtf(sq * (1.0f / CD) + 1e-5f);
  #pragma unroll
  for (int i = 0; i < 3; ++i) {
    int d = threadIdx.x + i * 256;
    float o = (v[i] - mean) * rstd * gs[d] + gb[d];
    x[(size_t)srow * CD + d] = o;
    xb[(size_t)srow * CD + d] = __float2bfloat16(o);
  }
}

// ---------------- MFMA GEMM: C = A(bf16 MxKtot) * Bt(bf16 NxKtot)^T + bias ----------------
// SPLITS>1: grid.z splits K; partial z writes fp32 to Cout + z*M*N; bias only in z==0.
template<int GELU, int OUTBF16, int SPLITS>
__global__ __launch_bounds__(256) void gemm_mfma(
    const bf16* __restrict__ A, const bf16* __restrict__ Bt,
    const float* __restrict__ bias, void* __restrict__ Cout,
    int M, int N, int Ktot) {
  __shared__ __align__(16) bf16 As[128 * 32];
  __shared__ __align__(16) bf16 Bs[128 * 32];
  const int tid = threadIdx.x;
  const int wave = tid >> 6, lane = tid & 63;
  const int m0 = blockIdx.y * 128, n0 = blockIdx.x * 128;
  const int wm = (wave & 1) * 64, wn = (wave >> 1) * 64;
  const int quad = lane >> 4, rsel = lane & 15;
  const int r_in = lane >> 2;
  const int chunk = lane & 3;
  const int Klen = Ktot / SPLITS;
  const int koff = (SPLITS > 1) ? blockIdx.z * Klen : 0;

  f32x4 acc[4][4] = {};

  for (int k0 = 0; k0 < Klen; k0 += 32) {
    #pragma unroll
    for (int i = 0; i < 4; ++i) {
      int op = wave * 4 + i;
      if (op < 8) {
        int row = op * 16 + r_in;
        gload_lds16(A + (size_t)(m0 + row) * Ktot + koff + k0 + chunk * 8, &As[op * 512]);
      } else {
        int row = (op - 8) * 16 + r_in;
        gload_lds16(Bt + (size_t)(n0 + row) * Ktot + koff + k0 + chunk * 8, &Bs[(op - 8) * 512]);
      }
    }
    __syncthreads();
    bf16x8 af[4], bfr[4];
    #pragma unroll
    for (int i = 0; i < 4; ++i)
      af[i] = *(const bf16x8*)&As[(wm + i * 16 + rsel) * 32 + quad * 8];
    #pragma unroll
    for (int j = 0; j < 4; ++j)
      bfr[j] = *(const bf16x8*)&Bs[(wn + j * 16 + rsel) * 32 + quad * 8];
    #pragma unroll
    for (int i = 0; i < 4; ++i)
      #pragma unroll
      for (int j = 0; j < 4; ++j)
        acc[i][j] = __builtin_amdgcn_mfma_f32_16x16x32_bf16(af[i], bfr[j], acc[i][j], 0, 0, 0);
    __syncthreads();
  }
  #pragma unroll
  for (int j = 0; j < 4; ++j) {
    int col = n0 + wn + j * 16 + rsel;
    float bv = (SPLITS == 1 || blockIdx.z == 0) ? bias[col] : 0.f;
    #pragma unroll
    for (int i = 0; i < 4; ++i) {
      #pragma unroll
      for (int r = 0; r < 4; ++r) {
        int rowm = m0 + wm + i * 16 + quad * 4 + r;
        float v = acc[i][j][r] + bv;
        if (GELU) v = 0.5f * v * (1.0f + erff(v * 0.70710678118654752f));
        if (OUTBF16) ((bf16*)Cout)[(size_t)rowm * N + col] = __float2bfloat16(v);
        else ((float*)Cout)[(size_t)blockIdx.z * M * N + (size_t)rowm * N + col] = v;
      }
    }
  }
}

// ---------------- vT[h][dh][s] = V[s][h*64+dh] (from qkv +1536) ----------------
__global__ __launch_bounds__(256) void vtrans_kernel(
    const bf16* __restrict__ qkv, bf16* __restrict__ vT) {
  __shared__ bf16 t[64][72];
  int s0 = blockIdx.x * 64, h = blockIdx.y;
  int r = threadIdx.x >> 2, cc = (threadIdx.x & 3) * 16;
  const bf16* src = qkv + (size_t)(s0 + r) * QKVN + 1536 + h * CDH + cc;
  *(bf16x8*)&t[r][cc] = *(const bf16x8*)src;
  *(bf16x8*)&t[r][cc + 8] = *(const bf16x8*)(src + 8);
  __syncthreads();
  int dh = threadIdx.x >> 2, sc = (threadIdx.x & 3) * 16;
  bf16 tmp[16];
  #pragma unroll
  for (int j = 0; j < 16; ++j) tmp[j] = t[sc + j][dh];
  bf16* dst = vT + (size_t)(h * CDH + dh) * CS + s0 + sc;
  *(bf16x8*)dst = *(bf16x8*)&tmp[0];
  *(bf16x8*)(dst + 8) = *(bf16x8*)&tmp[8];
}

// ---------------- MFMA flash attention (banded), syncless ----------------
// grid (S/64, H); block 256 = 4 independent waves; wave owns 16 queries.
// K fragments read directly from qkv (B-operand = K[key][dh], contiguous dh);
// V fragments read directly from vT (B-operand = V^T[dh][key], contiguous key).
// P round-trips through per-wave LDS. No __syncthreads anywhere.
__global__ __launch_bounds__(256) void attn_mfma(
    const bf16* __restrict__ qkv, const bf16* __restrict__ vT,
    const int* __restrict__ mask, bf16* __restrict__ ctx) {
  __shared__ bf16 Ps[4][16][72];
  const int h = blockIdx.y;
  const int q0 = blockIdx.x * 64;
  const int tid = threadIdx.x;
  const int wv = tid >> 6, lane = tid & 63;
  const int quad = lane >> 4, rsel = lane & 15;
  const int qw = q0 + wv * 16;

  const bf16* qp = &qkv[(size_t)(qw + rsel) * QKVN + h * CDH + quad * 8];
  bf16x8 qf0 = *(const bf16x8*)qp;
  bf16x8 qf1 = *(const bf16x8*)(qp + 32);

  float mi[4], li[4];
  f32x4 o[4] = {};
  #pragma unroll
  for (int r = 0; r < 4; ++r) { mi[r] = -1e30f; li[r] = 0.f; }

  #pragma unroll 1
  for (int kt = 0; kt < 9; ++kt) {
    int kbase = qw - CW + kt * 64;
    if (kbase + 63 < 0 || kbase >= CS) continue;

    // ---- QK^T: 16 queries x 64 keys ----
    f32x4 sc[4];
    #pragma unroll
    for (int nt = 0; nt < 4; ++nt) {
      int pp = kbase + nt * 16 + rsel;
      int ppc = min(max(pp, 0), CS - 1);
      const bf16* kp = &qkv[(size_t)ppc * QKVN + 768 + h * CDH + quad * 8];
      bf16x8 kf0 = *(const bf16x8*)kp;
      bf16x8 kf1 = *(const bf16x8*)(kp + 32);
      f32x4 z = {};
      z = __builtin_amdgcn_mfma_f32_16x16x32_bf16(qf0, kf0, z, 0, 0, 0);
      z = __builtin_amdgcn_mfma_f32_16x16x32_bf16(qf1, kf1, z, 0, 0, 0);
      sc[nt] = z;
    }
    // ---- mask + scale; row-wise max (rows live across 16-lane rsel groups) ----
    float mx[4] = {-1e30f, -1e30f, -1e30f, -1e30f};
    #pragma unroll
    for (int nt = 0; nt < 4; ++nt) {
      int pp = kbase + nt * 16 + rsel;
      int ppc = min(max(pp, 0), CS - 1);
      bool kvld = (pp >= 0) && (pp < CS) && (mask[ppc] != 0);
      #pragma unroll
      for (int r = 0; r < 4; ++r) {
        int qr = qw + quad * 4 + r;
        float s = sc[nt][r] * 0.125f;
        bool band = (pp >= qr - CW) && (pp <= qr + CW);
        s = (kvld && band) ? s : -1e9f;
        sc[nt][r] = s;
        mx[r] = fmaxf(mx[r], s);
      }
    }
    #pragma unroll
    for (int r = 0; r < 4; ++r) {
      #pragma unroll
      for (int off = 1; off < 16; off <<= 1)
        mx[r] = fmaxf(mx[r], __shfl_xor(mx[r], off, 64));
    }
    float al[4], rs[4] = {};
    #pragma unroll
    for (int r = 0; r < 4; ++r) {
      float mn = fmaxf(mi[r], mx[r]);
      al[r] = __expf(mi[r] - mn);
      mi[r] = mn;
    }
    #pragma unroll
    for (int nt = 0; nt < 4; ++nt)
      #pragma unroll
      for (int r = 0; r < 4; ++r) {
        float p = __expf(sc[nt][r] - mi[r]);
        sc[nt][r] = p;
        rs[r] += p;
      }
    #pragma unroll
    for (int r = 0; r < 4; ++r) {
      #pragma unroll
      for (int off = 1; off < 16; off <<= 1)
        rs[r] += __shfl_xor(rs[r], off, 64);
      li[r] = li[r] * al[r] + rs[r];
    }
    #pragma unroll
    for (int d = 0; d < 4; ++d)
      #pragma unroll
      for (int r = 0; r < 4; ++r) o[d][r] *= al[r];
    // ---- P -> per-wave LDS (C layout -> A layout) ----
    #pragma unroll
    for (int nt = 0; nt < 4; ++nt)
      #pragma unroll
      for (int r = 0; r < 4; ++r)
        Ps[wv][quad * 4 + r][nt * 16 + rsel] = __float2bfloat16(sc[nt][r]);
    __asm__ volatile("s_waitcnt lgkmcnt(0)" ::: "memory");
    bf16x8 pf0 = *(const bf16x8*)&Ps[wv][rsel][quad * 8];
    bf16x8 pf1 = *(const bf16x8*)&Ps[wv][rsel][32 + quad * 8];
    // ---- PV: B fragments straight from vT (clamped, contiguous keys) ----
    int kc0 = min(max(kbase + quad * 8, 0), CS - 8);
    int kc1 = min(max(kbase + 32 + quad * 8, 0), CS - 8);
    #pragma unroll
    for (int d = 0; d < 4; ++d) {
      const bf16* vrow = &vT[(size_t)(h * CDH + d * 16 + rsel) * CS];
      bf16x8 vf0 = *(const bf16x8*)(vrow + kc0);
      bf16x8 vf1 = *(const bf16x8*)(vrow + kc1);
      o[d] = __builtin_amdgcn_mfma_f32_16x16x32_bf16(pf0, vf0, o[d], 0, 0, 0);
      o[d] = __builtin_amdgcn_mfma_f32_16x16x32_bf16(pf1, vf1, o[d], 0, 0, 0);
    }
  }
  float inv[4];
  #pragma unroll
  for (int r = 0; r < 4; ++r) inv[r] = 1.0f / li[r];
  #pragma unroll
  for (int d = 0; d < 4; ++d)
    #pragma unroll
    for (int r = 0; r < 4; ++r)
      ctx[(size_t)(qw + quad * 4 + r) * CD + h * CDH + d * 16 + rsel] =
          __float2bfloat16(o[d][r] * inv[r]);
}

// ---------------- xout = LN(xin + sum_p g[p]); also writes xb (bf16) ----------------
template<int P>
__global__ __launch_bounds__(256) void add_ln_kernel(
    const float* __restrict__ g, const float* __restrict__ xin,
    float* __restrict__ xout, bf16* __restrict__ xb,
    const float* __restrict__ gs, const float* __restrict__ gb) {
  __shared__ float red[4];
  int srow = blockIdx.x;
  float v[3];
  #pragma unroll
  for (int i = 0; i < 3; ++i) {
    int d = threadIdx.x + i * 256;
    size_t idx = (size_t)srow * CD + d;
    float a = xin[idx];
    #pragma unroll
    for (int p = 0; p < P; ++p) a += g[p * SDC + idx];
    v[i] = a;
  }
  float sum = v[0] + v[1] + v[2];
  sum = block_reduce_sum(sum, red);
  float mean = sum * (1.0f / CD);
  float sq = 0.f;
  #pragma unroll
  for (int i = 0; i < 3; ++i) { float c = v[i] - mean; sq += c * c; }
  sq = block_reduce_sum(sq, red);
  float rstd = rsqrtf(sq * (1.0f / CD) + 1e-5f);
  #pragma unroll
  for (int i = 0; i < 3; ++i) {
    int d = threadIdx.x + i * 256;
    float o = (v[i] - mean) * rstd * gs[d] + gb[d];
    xout[(size_t)srow * CD + d] = o;
    xb[(size_t)srow * CD + d] = __float2bfloat16(o);
  }
}

// ---------------- pooled = tanh(x[0] @ pool_W + pool_b) ----------------
__global__ __launch_bounds__(256) void pool_kernel(
    const float* __restrict__ x, const float* __restrict__ Wp,
    const float* __restrict__ bp, float* __restrict__ out) {
  __shared__ float xs[CD];
  __shared__ float red[4][64];
  int t = threadIdx.x;
  for (int i = t; i < CD; i += 256) xs[i] = x[i];
  __syncthreads();
  int n = blockIdx.x * 64 + (t & 63);
  int kp = t >> 6;
  float acc = 0.f;
  #pragma unroll 4
  for (int kk = kp * 192; kk < kp * 192 + 192; ++kk)
    acc = fmaf(xs[kk], Wp[(size_t)kk * CD + n], acc);
  red[kp][t & 63] = acc;
  __syncthreads();
  if (t < 64) {
    int nn = blockIdx.x * 64 + t;
    out[nn] = tanhf(red[0][t] + red[1][t] + red[2][t] + red[3][t] + bp[nn]);
  }
}

extern "C" void kernel_launch(void* const* d_in, const int* in_sizes, int n_in,
                              void* d_out, int out_size, void* d_ws, size_t ws_size,
                              hipStream_t stream) {
  const int*   ids   = (const int*)d_in[0];
  const int*   mask  = (const int*)d_in[1];
  const float* wemb  = (const float*)d_in[2];
  const float* pemb  = (const float*)d_in[3];
  const float* temb  = (const float*)d_in[4];
  const float* elns  = (const float*)d_in[5];
  const float* elnb  = (const float*)d_in[6];
  const float* Wqkv  = (const float*)d_in[7];
  const float* bqkv  = (const float*)d_in[8];
  const float* Wo    = (const float*)d_in[9];
  const float* bo    = (const float*)d_in[10];
  const float* ln1s  = (const float*)d_in[11];
  const float* ln1b  = (const float*)d_in[12];
  const float* W1    = (const float*)d_in[13];
  const float* b1    = (const float*)d_in[14];
  const float* W2    = (const float*)d_in[15];
  const float* b2    = (const float*)d_in[16];
  const float* ln2s  = (const float*)d_in[17];
  const float* ln2b  = (const float*)d_in[18];
  const float* poolW = (const float*)d_in[19];
  const float* poolb = (const float*)d_in[20];

  const size_t SD = SDC;
  const size_t SF = (size_t)CS * CF;

  char* w = (char*)d_ws;
  float* x    = (float*)w; w += SD * 4;
  bf16*  xb   = (bf16*)w;  w += SD * 2;
  bf16*  qkv  = (bf16*)w;  w += (size_t)CS * QKVN * 2;
  bf16*  vT   = (bf16*)w;  w += SD * 2;
  bf16*  ctxb = (bf16*)w;  w += SD * 2;
  bf16*  t1b  = (bf16*)w;  w += SF * 2;
  float* t2   = (float*)w; w += SD * 4 * 4;   // 4 split-K partials
  int*   pos  = (int*)w;   w += (size_t)CS * 4;
  bf16* WqkvT = (bf16*)w;  w += (size_t)CL * QKVN * CD * 2;
  bf16* WoT   = (bf16*)w;  w += (size_t)CL * CD * CD * 2;
  bf16* W1T   = (bf16*)w;  w += (size_t)CL * CF * CD * 2;
  bf16* W2T   = (bf16*)w;  w += (size_t)CL * CD * CF * 2;

  dim3 tb(32, 8);
  scan_kernel<<<1, 256, 0, stream>>>(mask, pos);
  transpose_conv<<<dim3(CD/32, CD/32, CL*3), tb, 0, stream>>>(Wqkv, WqkvT, CD, CD);
  transpose_conv<<<dim3(CD/32, CD/32, CL),   tb, 0, stream>>>(Wo,   WoT,   CD, CD);
  transpose_conv<<<dim3(CF/32, CD/32, CL),   tb, 0, stream>>>(W1,   W1T,   CD, CF);
  transpose_conv<<<dim3(CD/32, CF/32, CL),   tb, 0, stream>>>(W2,   W2T,   CF, CD);
  embed_ln_kernel<<<CS, 256, 0, stream>>>(ids, pos, wemb, pemb, temb, elns, elnb, x, xb);

  for (int l = 0; l < CL; ++l) {
    gemm_mfma<0,1,1><<<dim3(QKVN/128, CS/128), 256, 0, stream>>>(
        xb, WqkvT + (size_t)l * QKVN * CD, bqkv + (size_t)l * 3 * CD, qkv, CS, QKVN, CD);
    vtrans_kernel<<<dim3(CS/64, CH), 256, 0, stream>>>(qkv, vT);
    attn_mfma<<<dim3(CS/64, CH), 256, 0, stream>>>(qkv, vT, mask, ctxb);
    gemm_mfma<0,0,2><<<dim3(CD/128, CS/128, 2), 256, 0, stream>>>(
        ctxb, WoT + (size_t)l * CD * CD, bo + (size_t)l * CD, t2, CS, CD, CD);
    add_ln_kernel<2><<<CS, 256, 0, stream>>>(t2, x, x, xb,
        ln1s + (size_t)l * CD, ln1b + (size_t)l * CD);
    gemm_mfma<1,1,1><<<dim3(CF/128, CS/128), 256, 0, stream>>>(
        xb, W1T + (size_t)l * CF * CD, b1 + (size_t)l * CF, t1b, CS, CF, CD);
    gemm_mfma<0,0,4><<<dim3(CD/128, CS/128, 4), 256, 0, stream>>>(
        t1b, W2T + (size_t)l * CD * CF, b2 + (size_t)l * CD, t2, CS, CD, CF);
    float* lastx = (l == CL - 1) ? (float*)d_out : x;
    add_ln_kernel<4><<<CS, 256, 0, stream>>>(t2, x, lastx, xb,
        ln2s + (size_t)l * CD, ln2b + (size_t)l * CD);
  }

  pool_kernel<<<12, 256, 0, stream>>>((float*)d_out, poolW, poolb, (float*)d_out + SD);
}

// Round 6
// 598.727 us; speedup vs baseline: 3.8975x; 1.0305x over previous
//
#include <hip/hip_runtime.h>
#include <hip/hip_bf16.h>
#include <math.h>
#include <stddef.h>
#include <stdint.h>

typedef __hip_bfloat16 bf16;
typedef short bf16x8 __attribute__((ext_vector_type(8)));
typedef float f32x4 __attribute__((ext_vector_type(4)));

#define CS 2048   // S
#define CD 768    // D
#define CH 12     // H
#define CDH 64    // DH
#define CF 3072   // F
#define CW 256    // W
#define CL 2      // L
#define QKVN 2304 // 3*D fused qkv width
#define SDC ((size_t)CS * CD)

// ---------------- async global->LDS, 16B per lane ----------------
__device__ __forceinline__ void gload_lds16(const bf16* g, bf16* l) {
  __builtin_amdgcn_global_load_lds(
      (const __attribute__((address_space(1))) void*)g,
      (__attribute__((address_space(3))) void*)l, 16, 0, 0);
}

__device__ __forceinline__ unsigned short f2bu(float v) {
  bf16 b = __float2bfloat16(v);
  return *(unsigned short*)&b;
}

// ---------------- block reduction (256 threads = 4 waves) ----------------
__device__ __forceinline__ float block_reduce_sum(float v, float* buf) {
  #pragma unroll
  for (int off = 32; off > 0; off >>= 1) v += __shfl_down(v, off, 64);
  int wid = threadIdx.x >> 6;
  __syncthreads();
  if ((threadIdx.x & 63) == 0) buf[wid] = v;
  __syncthreads();
  if (threadIdx.x == 0) buf[0] = buf[0] + buf[1] + buf[2] + buf[3];
  __syncthreads();
  return buf[0];
}

// ---------------- pos_ids = cumsum(mask)*mask + 1 ----------------
__global__ __launch_bounds__(256) void scan_kernel(const int* __restrict__ mask,
                                                   int* __restrict__ pos) {
  __shared__ int part[256];
  int tid = threadIdx.x;
  int mv[8]; int s = 0;
  #pragma unroll
  for (int i = 0; i < 8; ++i) { mv[i] = mask[tid * 8 + i]; s += mv[i]; }
  part[tid] = s;
  __syncthreads();
  for (int off = 1; off < 256; off <<= 1) {
    int t = 0;
    if (tid >= off) t = part[tid - off];
    __syncthreads();
    part[tid] += t;
    __syncthreads();
  }
  int run = part[tid] - s;
  #pragma unroll
  for (int i = 0; i < 8; ++i) {
    run += mv[i];
    pos[tid * 8 + i] = run * mv[i] + 1;
  }
}

// ---------------- all-weights transpose + fp32->bf16, single dispatch ----------------
// 13824 blocks of 32x32 tiles: [0,3456) Wqkv, [3456,4608) Wo, [4608,9216) W1, [9216,13824) W2.
__global__ __launch_bounds__(256) void transpose_all(
    const float* __restrict__ Wqkv, const float* __restrict__ Wo,
    const float* __restrict__ W1, const float* __restrict__ W2,
    bf16* __restrict__ WqkvT, bf16* __restrict__ WoT,
    bf16* __restrict__ W1T, bf16* __restrict__ W2T) {
  __shared__ float tile[32][33];
  int b = blockIdx.x;
  const float* src; bf16* dst; int K, N, t;
  if (b < 3456) {
    int mat = b / 576; t = b % 576; K = 768; N = 768;
    src = Wqkv + (size_t)mat * 768 * 768; dst = WqkvT + (size_t)mat * 768 * 768;
  } else if (b < 4608) {
    b -= 3456; int mat = b / 576; t = b % 576; K = 768; N = 768;
    src = Wo + (size_t)mat * 768 * 768; dst = WoT + (size_t)mat * 768 * 768;
  } else if (b < 9216) {
    b -= 4608; int mat = b / 2304; t = b % 2304; K = 768; N = 3072;
    src = W1 + (size_t)mat * 768 * 3072; dst = W1T + (size_t)mat * 768 * 3072;
  } else {
    b -= 9216; int mat = b / 2304; t = b % 2304; K = 3072; N = 768;
    src = W2 + (size_t)mat * 3072 * 768; dst = W2T + (size_t)mat * 3072 * 768;
  }
  int nt = N / 32;
  int bn = (t % nt) * 32, bk = (t / nt) * 32;
  int tx = threadIdx.x & 31, ty = (threadIdx.x >> 5) & 7;
  #pragma unroll
  for (int i = 0; i < 32; i += 8)
    tile[ty + i][tx] = src[(size_t)(bk + ty + i) * N + bn + tx];
  __syncthreads();
  #pragma unroll
  for (int i = 0; i < 32; i += 8)
    dst[(size_t)(bn + ty + i) * K + bk + tx] = __float2bfloat16(tile[tx][ty + i]);
}

// ---------------- embedding gather + LN -> x (f32) + xb (bf16) ----------------
__global__ __launch_bounds__(256) void embed_ln_kernel(
    const int* __restrict__ ids, const int* __restrict__ pos,
    const float* __restrict__ wemb, const float* __restrict__ pemb,
    const float* __restrict__ temb, const float* __restrict__ gs,
    const float* __restrict__ gb, float* __restrict__ x, bf16* __restrict__ xb) {
  __shared__ float red[4];
  int srow = blockIdx.x;
  long long id = ids[srow];
  long long pid = pos[srow];
  float v[3];
  #pragma unroll
  for (int i = 0; i < 3; ++i) {
    int d = threadIdx.x + i * 256;
    v[i] = wemb[id * CD + d] + pemb[pid * CD + d] + temb[d];
  }
  float sum = v[0] + v[1] + v[2];
  sum = block_reduce_sum(sum, red);
  float mean = sum * (1.0f / CD);
  float sq = 0.f;
  #pragma unroll
  for (int i = 0; i < 3; ++i) { float c = v[i] - mean; sq += c * c; }
  sq = block_reduce_sum(sq, red);
  float rstd = rsqrtf(sq * (1.0f / CD) + 1e-5f);
  #pragma unroll
  for (int i = 0; i < 3; ++i) {
    int d = threadIdx.x + i * 256;
    float o = (v[i] - mean) * rstd * gs[d] + gb[d];
    x[(size_t)srow * CD + d] = o;
    xb[(size_t)srow * CD + d] = __float2bfloat16(o);
  }
}

// ---------------- MFMA GEMM: C = A(bf16 MxKtot) * Bt(bf16 NxKtot)^T + bias ----------------
// SPLITS>1: grid.z splits K; partial z writes fp32 to Cout + z*M*N; bias only in z==0.
// VTFUSE: cols >= 1536 (block-uniform) go transposed to vTout[(col-1536)*CS+row] instead of Cout.
template<int GELU, int OUTBF16, int SPLITS, int VTFUSE>
__global__ __launch_bounds__(256) void gemm_mfma(
    const bf16* __restrict__ A, const bf16* __restrict__ Bt,
    const float* __restrict__ bias, void* __restrict__ Cout,
    bf16* __restrict__ vTout, int M, int N, int Ktot) {
  __shared__ __align__(16) bf16 As[128 * 32];
  __shared__ __align__(16) bf16 Bs[128 * 32];
  const int tid = threadIdx.x;
  const int wave = tid >> 6, lane = tid & 63;
  const int m0 = blockIdx.y * 128, n0 = blockIdx.x * 128;
  const int wm = (wave & 1) * 64, wn = (wave >> 1) * 64;
  const int quad = lane >> 4, rsel = lane & 15;
  const int r_in = lane >> 2;
  const int chunk = lane & 3;
  const int Klen = Ktot / SPLITS;
  const int koff = (SPLITS > 1) ? blockIdx.z * Klen : 0;

  f32x4 acc[4][4] = {};

  for (int k0 = 0; k0 < Klen; k0 += 32) {
    #pragma unroll
    for (int i = 0; i < 4; ++i) {
      int op = wave * 4 + i;
      if (op < 8) {
        int row = op * 16 + r_in;
        gload_lds16(A + (size_t)(m0 + row) * Ktot + koff + k0 + chunk * 8, &As[op * 512]);
      } else {
        int row = (op - 8) * 16 + r_in;
        gload_lds16(Bt + (size_t)(n0 + row) * Ktot + koff + k0 + chunk * 8, &Bs[(op - 8) * 512]);
      }
    }
    __syncthreads();
    bf16x8 af[4], bfr[4];
    #pragma unroll
    for (int i = 0; i < 4; ++i)
      af[i] = *(const bf16x8*)&As[(wm + i * 16 + rsel) * 32 + quad * 8];
    #pragma unroll
    for (int j = 0; j < 4; ++j)
      bfr[j] = *(const bf16x8*)&Bs[(wn + j * 16 + rsel) * 32 + quad * 8];
    #pragma unroll
    for (int i = 0; i < 4; ++i)
      #pragma unroll
      for (int j = 0; j < 4; ++j)
        acc[i][j] = __builtin_amdgcn_mfma_f32_16x16x32_bf16(af[i], bfr[j], acc[i][j], 0, 0, 0);
    __syncthreads();
  }
  #pragma unroll
  for (int j = 0; j < 4; ++j) {
    int col = n0 + wn + j * 16 + rsel;
    float bv = (SPLITS == 1 || blockIdx.z == 0) ? bias[col] : 0.f;
    if (VTFUSE && col >= 1536) {
      // V columns: write transposed, packed 4 rows (8B) per (i) chunk
      #pragma unroll
      for (int i = 0; i < 4; ++i) {
        int rowb = m0 + wm + i * 16 + quad * 4;
        ushort4 pk;
        pk.x = f2bu(acc[i][j][0] + bv);
        pk.y = f2bu(acc[i][j][1] + bv);
        pk.z = f2bu(acc[i][j][2] + bv);
        pk.w = f2bu(acc[i][j][3] + bv);
        *(ushort4*)&vTout[(size_t)(col - 1536) * CS + rowb] = pk;
      }
    } else {
      #pragma unroll
      for (int i = 0; i < 4; ++i) {
        #pragma unroll
        for (int r = 0; r < 4; ++r) {
          int rowm = m0 + wm + i * 16 + quad * 4 + r;
          float v = acc[i][j][r] + bv;
          if (GELU) v = 0.5f * v * (1.0f + erff(v * 0.70710678118654752f));
          if (OUTBF16) ((bf16*)Cout)[(size_t)rowm * N + col] = __float2bfloat16(v);
          else ((float*)Cout)[(size_t)blockIdx.z * M * N + (size_t)rowm * N + col] = v;
        }
      }
    }
  }
}

// ---------------- MFMA flash attention (banded), key-split x2 ----------------
// grid (S/64, H); block 512 = 8 waves = 4 query-groups x 2 key-halves.
// Wave (qg, half) does tiles kt in [half?5:0, half?9:5). Halves merge via LDS.
__global__ __launch_bounds__(512) void attn_mfma(
    const bf16* __restrict__ qkv, const bf16* __restrict__ vT,
    const int* __restrict__ mask, bf16* __restrict__ ctx) {
  __shared__ bf16 Ps[8][16][72];
  __shared__ float Obuf[4][16][64];
  __shared__ float Mbuf[4][16];
  __shared__ float Lbuf[4][16];
  const int h = blockIdx.y;
  const int q0 = blockIdx.x * 64;
  const int tid = threadIdx.x;
  const int wv = tid >> 6, lane = tid & 63;
  const int qg = wv & 3, half = wv >> 2;
  const int quad = lane >> 4, rsel = lane & 15;
  const int qw = q0 + qg * 16;

  const bf16* qp = &qkv[(size_t)(qw + rsel) * QKVN + h * CDH + quad * 8];
  bf16x8 qf0 = *(const bf16x8*)qp;
  bf16x8 qf1 = *(const bf16x8*)(qp + 32);

  float mi[4], li[4];
  f32x4 o[4] = {};
  #pragma unroll
  for (int r = 0; r < 4; ++r) { mi[r] = -1e30f; li[r] = 0.f; }

  const int kt0 = half ? 5 : 0, kt1 = half ? 9 : 5;
  #pragma unroll 1
  for (int kt = kt0; kt < kt1; ++kt) {
    int kbase = qw - CW + kt * 64;
    if (kbase + 63 < 0 || kbase >= CS) continue;

    // ---- QK^T: 16 queries x 64 keys ----
    f32x4 sc[4];
    #pragma unroll
    for (int nt = 0; nt < 4; ++nt) {
      int pp = kbase + nt * 16 + rsel;
      int ppc = min(max(pp, 0), CS - 1);
      const bf16* kp = &qkv[(size_t)ppc * QKVN + 768 + h * CDH + quad * 8];
      bf16x8 kf0 = *(const bf16x8*)kp;
      bf16x8 kf1 = *(const bf16x8*)(kp + 32);
      f32x4 z = {};
      z = __builtin_amdgcn_mfma_f32_16x16x32_bf16(qf0, kf0, z, 0, 0, 0);
      z = __builtin_amdgcn_mfma_f32_16x16x32_bf16(qf1, kf1, z, 0, 0, 0);
      sc[nt] = z;
    }
    // ---- mask + scale; row max over the 16-lane rsel group ----
    float mx[4] = {-1e30f, -1e30f, -1e30f, -1e30f};
    #pragma unroll
    for (int nt = 0; nt < 4; ++nt) {
      int pp = kbase + nt * 16 + rsel;
      int ppc = min(max(pp, 0), CS - 1);
      bool kvld = (pp >= 0) && (pp < CS) && (mask[ppc] != 0);
      #pragma unroll
      for (int r = 0; r < 4; ++r) {
        int qr = qw + quad * 4 + r;
        float s = sc[nt][r] * 0.125f;
        bool band = (pp >= qr - CW) && (pp <= qr + CW);
        s = (kvld && band) ? s : -1e9f;
        sc[nt][r] = s;
        mx[r] = fmaxf(mx[r], s);
      }
    }
    #pragma unroll
    for (int r = 0; r < 4; ++r) {
      #pragma unroll
      for (int off = 1; off < 16; off <<= 1)
        mx[r] = fmaxf(mx[r], __shfl_xor(mx[r], off, 64));
    }
    float al[4], rs[4] = {};
    #pragma unroll
    for (int r = 0; r < 4; ++r) {
      float mn = fmaxf(mi[r], mx[r]);
      al[r] = __expf(mi[r] - mn);
      mi[r] = mn;
    }
    #pragma unroll
    for (int nt = 0; nt < 4; ++nt)
      #pragma unroll
      for (int r = 0; r < 4; ++r) {
        float p = __expf(sc[nt][r] - mi[r]);
        sc[nt][r] = p;
        rs[r] += p;
      }
    #pragma unroll
    for (int r = 0; r < 4; ++r) {
      #pragma unroll
      for (int off = 1; off < 16; off <<= 1)
        rs[r] += __shfl_xor(rs[r], off, 64);
      li[r] = li[r] * al[r] + rs[r];
    }
    #pragma unroll
    for (int d = 0; d < 4; ++d)
      #pragma unroll
      for (int r = 0; r < 4; ++r) o[d][r] *= al[r];
    // ---- P -> per-wave LDS (C layout -> A layout) ----
    #pragma unroll
    for (int nt = 0; nt < 4; ++nt)
      #pragma unroll
      for (int r = 0; r < 4; ++r)
        Ps[wv][quad * 4 + r][nt * 16 + rsel] = __float2bfloat16(sc[nt][r]);
    __asm__ volatile("s_waitcnt lgkmcnt(0)" ::: "memory");
    bf16x8 pf0 = *(const bf16x8*)&Ps[wv][rsel][quad * 8];
    bf16x8 pf1 = *(const bf16x8*)&Ps[wv][rsel][32 + quad * 8];
    // ---- PV from vT (clamped, contiguous keys) ----
    int kc0 = min(max(kbase + quad * 8, 0), CS - 8);
    int kc1 = min(max(kbase + 32 + quad * 8, 0), CS - 8);
    #pragma unroll
    for (int d = 0; d < 4; ++d) {
      const bf16* vrow = &vT[(size_t)(h * CDH + d * 16 + rsel) * CS];
      bf16x8 vf0 = *(const bf16x8*)(vrow + kc0);
      bf16x8 vf1 = *(const bf16x8*)(vrow + kc1);
      o[d] = __builtin_amdgcn_mfma_f32_16x16x32_bf16(pf0, vf0, o[d], 0, 0, 0);
      o[d] = __builtin_amdgcn_mfma_f32_16x16x32_bf16(pf1, vf1, o[d], 0, 0, 0);
    }
  }

  // ---- merge halves ----
  if (half == 1) {
    #pragma unroll
    for (int d = 0; d < 4; ++d)
      #pragma unroll
      for (int r = 0; r < 4; ++r)
        Obuf[qg][quad * 4 + r][d * 16 + rsel] = o[d][r];
    if (rsel == 0) {
      #pragma unroll
      for (int r = 0; r < 4; ++r) {
        Mbuf[qg][quad * 4 + r] = mi[r];
        Lbuf[qg][quad * 4 + r] = li[r];
      }
    }
  }
  __syncthreads();
  if (half == 0) {
    #pragma unroll
    for (int r = 0; r < 4; ++r) {
      int row = quad * 4 + r;
      float m1 = Mbuf[qg][row], l1 = Lbuf[qg][row];
      float mn = fmaxf(mi[r], m1);
      float a0 = __expf(mi[r] - mn);
      float a1 = __expf(m1 - mn);
      float inv = 1.0f / (li[r] * a0 + l1 * a1);
      #pragma unroll
      for (int d = 0; d < 4; ++d) {
        float val = (o[d][r] * a0 + Obuf[qg][row][d * 16 + rsel] * a1) * inv;
        ctx[(size_t)(qw + row) * CD + h * CDH + d * 16 + rsel] = __float2bfloat16(val);
      }
    }
  }
}

// ---------------- xout = LN(xin + sum_p g[p]); also writes xb (bf16) ----------------
template<int P>
__global__ __launch_bounds__(256) void add_ln_kernel(
    const float* __restrict__ g, const float* __restrict__ xin,
    float* __restrict__ xout, bf16* __restrict__ xb,
    const float* __restrict__ gs, const float* __restrict__ gb) {
  __shared__ float red[4];
  int srow = blockIdx.x;
  float v[3];
  #pragma unroll
  for (int i = 0; i < 3; ++i) {
    int d = threadIdx.x + i * 256;
    size_t idx = (size_t)srow * CD + d;
    float a = xin[idx];
    #pragma unroll
    for (int p = 0; p < P; ++p) a += g[p * SDC + idx];
    v[i] = a;
  }
  float sum = v[0] + v[1] + v[2];
  sum = block_reduce_sum(sum, red);
  float mean = sum * (1.0f / CD);
  float sq = 0.f;
  #pragma unroll
  for (int i = 0; i < 3; ++i) { float c = v[i] - mean; sq += c * c; }
  sq = block_reduce_sum(sq, red);
  float rstd = rsqrtf(sq * (1.0f / CD) + 1e-5f);
  #pragma unroll
  for (int i = 0; i < 3; ++i) {
    int d = threadIdx.x + i * 256;
    float o = (v[i] - mean) * rstd * gs[d] + gb[d];
    xout[(size_t)srow * CD + d] = o;
    xb[(size_t)srow * CD + d] = __float2bfloat16(o);
  }
}

// ---------------- pooled = tanh(x[0] @ pool_W + pool_b) ----------------
__global__ __launch_bounds__(256) void pool_kernel(
    const float* __restrict__ x, const float* __restrict__ Wp,
    const float* __restrict__ bp, float* __restrict__ out) {
  __shared__ float xs[CD];
  __shared__ float red[4][64];
  int t = threadIdx.x;
  for (int i = t; i < CD; i += 256) xs[i] = x[i];
  __syncthreads();
  int n = blockIdx.x * 64 + (t & 63);
  int kp = t >> 6;
  float acc = 0.f;
  #pragma unroll 4
  for (int kk = kp * 192; kk < kp * 192 + 192; ++kk)
    acc = fmaf(xs[kk], Wp[(size_t)kk * CD + n], acc);
  red[kp][t & 63] = acc;
  __syncthreads();
  if (t < 64) {
    int nn = blockIdx.x * 64 + t;
    out[nn] = tanhf(red[0][t] + red[1][t] + red[2][t] + red[3][t] + bp[nn]);
  }
}

extern "C" void kernel_launch(void* const* d_in, const int* in_sizes, int n_in,
                              void* d_out, int out_size, void* d_ws, size_t ws_size,
                              hipStream_t stream) {
  const int*   ids   = (const int*)d_in[0];
  const int*   mask  = (const int*)d_in[1];
  const float* wemb  = (const float*)d_in[2];
  const float* pemb  = (const float*)d_in[3];
  const float* temb  = (const float*)d_in[4];
  const float* elns  = (const float*)d_in[5];
  const float* elnb  = (const float*)d_in[6];
  const float* Wqkv  = (const float*)d_in[7];
  const float* bqkv  = (const float*)d_in[8];
  const float* Wo    = (const float*)d_in[9];
  const float* bo    = (const float*)d_in[10];
  const float* ln1s  = (const float*)d_in[11];
  const float* ln1b  = (const float*)d_in[12];
  const float* W1    = (const float*)d_in[13];
  const float* b1    = (const float*)d_in[14];
  const float* W2    = (const float*)d_in[15];
  const float* b2    = (const float*)d_in[16];
  const float* ln2s  = (const float*)d_in[17];
  const float* ln2b  = (const float*)d_in[18];
  const float* poolW = (const float*)d_in[19];
  const float* poolb = (const float*)d_in[20];

  const size_t SD = SDC;
  const size_t SF = (size_t)CS * CF;

  char* w = (char*)d_ws;
  float* x    = (float*)w; w += SD * 4;
  bf16*  xb   = (bf16*)w;  w += SD * 2;
  bf16*  qkv  = (bf16*)w;  w += (size_t)CS * QKVN * 2;
  bf16*  vT   = (bf16*)w;  w += SD * 2;
  bf16*  ctxb = (bf16*)w;  w += SD * 2;
  bf16*  t1b  = (bf16*)w;  w += SF * 2;
  float* t2   = (float*)w; w += SD * 4 * 4;   // 4 split-K partials
  int*   pos  = (int*)w;   w += (size_t)CS * 4;
  bf16* WqkvT = (bf16*)w;  w += (size_t)CL * QKVN * CD * 2;
  bf16* WoT   = (bf16*)w;  w += (size_t)CL * CD * CD * 2;
  bf16* W1T   = (bf16*)w;  w += (size_t)CL * CF * CD * 2;
  bf16* W2T   = (bf16*)w;  w += (size_t)CL * CD * CF * 2;

  scan_kernel<<<1, 256, 0, stream>>>(mask, pos);
  transpose_all<<<13824, 256, 0, stream>>>(Wqkv, Wo, W1, W2, WqkvT, WoT, W1T, W2T);
  embed_ln_kernel<<<CS, 256, 0, stream>>>(ids, pos, wemb, pemb, temb, elns, elnb, x, xb);

  for (int l = 0; l < CL; ++l) {
    gemm_mfma<0,1,1,1><<<dim3(QKVN/128, CS/128), 256, 0, stream>>>(
        xb, WqkvT + (size_t)l * QKVN * CD, bqkv + (size_t)l * 3 * CD, qkv, vT, CS, QKVN, CD);
    attn_mfma<<<dim3(CS/64, CH), 512, 0, stream>>>(qkv, vT, mask, ctxb);
    gemm_mfma<0,0,2,0><<<dim3(CD/128, CS/128, 2), 256, 0, stream>>>(
        ctxb, WoT + (size_t)l * CD * CD, bo + (size_t)l * CD, t2, nullptr, CS, CD, CD);
    add_ln_kernel<2><<<CS, 256, 0, stream>>>(t2, x, x, xb,
        ln1s + (size_t)l * CD, ln1b + (size_t)l * CD);
    gemm_mfma<1,1,1,0><<<dim3(CF/128, CS/128), 256, 0, stream>>>(
        xb, W1T + (size_t)l * CF * CD, b1 + (size_t)l * CF, t1b, nullptr, CS, CF, CD);
    gemm_mfma<0,0,4,0><<<dim3(CD/128, CS/128, 4), 256, 0, stream>>>(
        t1b, W2T + (size_t)l * CD * CF, b2 + (size_t)l * CD, t2, nullptr, CS, CD, CF);
    float* lastx = (l == CL - 1) ? (float*)d_out : x;
    add_ln_kernel<4><<<CS, 256, 0, stream>>>(t2, x, lastx, xb,
        ln2s + (size_t)l * CD, ln2b + (size_t)l * CD);
  }

  pool_kernel<<<12, 256, 0, stream>>>((float*)d_out, poolW, poolb, (float*)d_out + SD);
}

// Round 7
// 561.156 us; speedup vs baseline: 4.1584x; 1.0670x over previous
//
#include <hip/hip_runtime.h>
#include <hip/hip_bf16.h>
#include <math.h>
#include <stddef.h>
#include <stdint.h>

typedef __hip_bfloat16 bf16;
typedef short bf16x8 __attribute__((ext_vector_type(8)));
typedef float f32x4 __attribute__((ext_vector_type(4)));

#define CS 2048   // S
#define CD 768    // D
#define CH 12     // H
#define CDH 64    // DH
#define CF 3072   // F
#define CW 256    // W
#define CL 2      // L
#define QKVN 2304 // 3*D fused qkv width
#define SDC ((size_t)CS * CD)

// ---------------- async global->LDS, 16B per lane ----------------
__device__ __forceinline__ void gload_lds16(const bf16* g, bf16* l) {
  __builtin_amdgcn_global_load_lds(
      (const __attribute__((address_space(1))) void*)g,
      (__attribute__((address_space(3))) void*)l, 16, 0, 0);
}

__device__ __forceinline__ unsigned short f2bu(float v) {
  bf16 b = __float2bfloat16(v);
  return *(unsigned short*)&b;
}

// ---------------- block reduction (256 threads = 4 waves) ----------------
__device__ __forceinline__ float block_reduce_sum(float v, float* buf) {
  #pragma unroll
  for (int off = 32; off > 0; off >>= 1) v += __shfl_down(v, off, 64);
  int wid = threadIdx.x >> 6;
  __syncthreads();
  if ((threadIdx.x & 63) == 0) buf[wid] = v;
  __syncthreads();
  if (threadIdx.x == 0) buf[0] = buf[0] + buf[1] + buf[2] + buf[3];
  __syncthreads();
  return buf[0];
}

// ---------------- all-weights transpose + fp32->bf16, single dispatch ----------------
__global__ __launch_bounds__(256) void transpose_all(
    const float* __restrict__ Wqkv, const float* __restrict__ Wo,
    const float* __restrict__ W1, const float* __restrict__ W2,
    bf16* __restrict__ WqkvT, bf16* __restrict__ WoT,
    bf16* __restrict__ W1T, bf16* __restrict__ W2T) {
  __shared__ float tile[32][33];
  int b = blockIdx.x;
  const float* src; bf16* dst; int K, N, t;
  if (b < 3456) {
    int mat = b / 576; t = b % 576; K = 768; N = 768;
    src = Wqkv + (size_t)mat * 768 * 768; dst = WqkvT + (size_t)mat * 768 * 768;
  } else if (b < 4608) {
    b -= 3456; int mat = b / 576; t = b % 576; K = 768; N = 768;
    src = Wo + (size_t)mat * 768 * 768; dst = WoT + (size_t)mat * 768 * 768;
  } else if (b < 9216) {
    b -= 4608; int mat = b / 2304; t = b % 2304; K = 768; N = 3072;
    src = W1 + (size_t)mat * 768 * 3072; dst = W1T + (size_t)mat * 768 * 3072;
  } else {
    b -= 9216; int mat = b / 2304; t = b % 2304; K = 3072; N = 768;
    src = W2 + (size_t)mat * 3072 * 768; dst = W2T + (size_t)mat * 3072 * 768;
  }
  int nt = N / 32;
  int bn = (t % nt) * 32, bk = (t / nt) * 32;
  int tx = threadIdx.x & 31, ty = (threadIdx.x >> 5) & 7;
  #pragma unroll
  for (int i = 0; i < 32; i += 8)
    tile[ty + i][tx] = src[(size_t)(bk + ty + i) * N + bn + tx];
  __syncthreads();
  #pragma unroll
  for (int i = 0; i < 32; i += 8)
    dst[(size_t)(bn + ty + i) * K + bk + tx] = __float2bfloat16(tile[tx][ty + i]);
}

// ---------------- embedding gather + LN (pos scan fused) ----------------
__global__ __launch_bounds__(256) void embed_ln_kernel(
    const int* __restrict__ ids, const int* __restrict__ mask,
    const float* __restrict__ wemb, const float* __restrict__ pemb,
    const float* __restrict__ temb, const float* __restrict__ gs,
    const float* __restrict__ gb, float* __restrict__ x, bf16* __restrict__ xb) {
  __shared__ float red[4];
  int srow = blockIdx.x;
  // pos_id = cumsum_inclusive(mask)[srow] * mask[srow] + 1, computed in-block
  float ps = 0.f;
  for (int i = threadIdx.x; i <= srow; i += 256) ps += (float)mask[i];
  float tot = block_reduce_sum(ps, red);
  long long pid = (long long)((int)(tot + 0.5f) * mask[srow] + 1);
  long long id = ids[srow];
  float v[3];
  #pragma unroll
  for (int i = 0; i < 3; ++i) {
    int d = threadIdx.x + i * 256;
    v[i] = wemb[id * CD + d] + pemb[pid * CD + d] + temb[d];
  }
  float sum = v[0] + v[1] + v[2];
  sum = block_reduce_sum(sum, red);
  float mean = sum * (1.0f / CD);
  float sq = 0.f;
  #pragma unroll
  for (int i = 0; i < 3; ++i) { float c = v[i] - mean; sq += c * c; }
  sq = block_reduce_sum(sq, red);
  float rstd = rsqrtf(sq * (1.0f / CD) + 1e-5f);
  #pragma unroll
  for (int i = 0; i < 3; ++i) {
    int d = threadIdx.x + i * 256;
    float o = (v[i] - mean) * rstd * gs[d] + gb[d];
    x[(size_t)srow * CD + d] = o;
    xb[(size_t)srow * CD + d] = __float2bfloat16(o);
  }
}

// ---------------- MFMA GEMM, BK=64, XOR-swizzled LDS ----------------
// C = A(bf16 MxKtot) * Bt(bf16 NxKtot)^T + bias.
// LDS slot (row, c') holds global 16B-chunk c' ^ (row&7); staging lanes load
// chunk (lane&7)^(lane>>3 &7); fragment reads XOR with (rsel&7). 2 lanes/bank.
// SPLITS>1: grid.z splits K; partial z writes BF16 to Cout + z*M*N; bias in z==0.
// VTFUSE: cols >= 1536 go transposed to vTout[(col-1536)*CS+row].
template<int GELU, int OUTBF16, int SPLITS, int VTFUSE>
__global__ __launch_bounds__(256) void gemm_mfma(
    const bf16* __restrict__ A, const bf16* __restrict__ Bt,
    const float* __restrict__ bias, void* __restrict__ Cout,
    bf16* __restrict__ vTout, int M, int N, int Ktot) {
  __shared__ __align__(16) bf16 As[128 * 64];
  __shared__ __align__(16) bf16 Bs[128 * 64];
  const int tid = threadIdx.x;
  const int wave = tid >> 6, lane = tid & 63;
  const int m0 = blockIdx.y * 128, n0 = blockIdx.x * 128;
  const int wm = (wave & 1) * 64, wn = (wave >> 1) * 64;
  const int quad = lane >> 4, rsel = lane & 15;
  const int rx = rsel & 7;
  const int r_in = lane >> 3;          // staging row within op (0..7)
  const int chunk = lane & 7;          // staging LDS chunk c'
  const int gchunk = chunk ^ r_in;     // global chunk to load
  const int Klen = Ktot / SPLITS;
  const int koff = (SPLITS > 1) ? blockIdx.z * Klen : 0;

  f32x4 acc[4][4] = {};

  for (int k0 = 0; k0 < Klen; k0 += 64) {
    #pragma unroll
    for (int i = 0; i < 8; ++i) {
      int op = wave * 8 + i;
      if (op < 16) {
        int row = op * 8 + r_in;
        gload_lds16(A + (size_t)(m0 + row) * Ktot + koff + k0 + gchunk * 8, &As[op * 512]);
      } else {
        int row = (op - 16) * 8 + r_in;
        gload_lds16(Bt + (size_t)(n0 + row) * Ktot + koff + k0 + gchunk * 8, &Bs[(op - 16) * 512]);
      }
    }
    __syncthreads();
    #pragma unroll
    for (int kh = 0; kh < 2; ++kh) {
      bf16x8 af[4], bfr[4];
      int cq = ((kh << 2) | quad);
      #pragma unroll
      for (int i = 0; i < 4; ++i)
        af[i] = *(const bf16x8*)&As[(wm + i * 16 + rsel) * 64 + (cq ^ rx) * 8];
      #pragma unroll
      for (int j = 0; j < 4; ++j)
        bfr[j] = *(const bf16x8*)&Bs[(wn + j * 16 + rsel) * 64 + (cq ^ rx) * 8];
      #pragma unroll
      for (int i = 0; i < 4; ++i)
        #pragma unroll
        for (int j = 0; j < 4; ++j)
          acc[i][j] = __builtin_amdgcn_mfma_f32_16x16x32_bf16(af[i], bfr[j], acc[i][j], 0, 0, 0);
    }
    __syncthreads();
  }
  #pragma unroll
  for (int j = 0; j < 4; ++j) {
    int col = n0 + wn + j * 16 + rsel;
    float bv = (SPLITS == 1 || blockIdx.z == 0) ? bias[col] : 0.f;
    if (VTFUSE && col >= 1536) {
      #pragma unroll
      for (int i = 0; i < 4; ++i) {
        int rowb = m0 + wm + i * 16 + quad * 4;
        ushort4 pk;
        pk.x = f2bu(acc[i][j][0] + bv);
        pk.y = f2bu(acc[i][j][1] + bv);
        pk.z = f2bu(acc[i][j][2] + bv);
        pk.w = f2bu(acc[i][j][3] + bv);
        *(ushort4*)&vTout[(size_t)(col - 1536) * CS + rowb] = pk;
      }
    } else {
      #pragma unroll
      for (int i = 0; i < 4; ++i) {
        #pragma unroll
        for (int r = 0; r < 4; ++r) {
          int rowm = m0 + wm + i * 16 + quad * 4 + r;
          float v = acc[i][j][r] + bv;
          if (GELU) v = 0.5f * v * (1.0f + erff(v * 0.70710678118654752f));
          if (SPLITS > 1)
            ((bf16*)Cout)[(size_t)blockIdx.z * M * N + (size_t)rowm * N + col] = __float2bfloat16(v);
          else if (OUTBF16)
            ((bf16*)Cout)[(size_t)rowm * N + col] = __float2bfloat16(v);
          else
            ((float*)Cout)[(size_t)rowm * N + col] = v;
        }
      }
    }
  }
}

// ---------------- MFMA flash attention (banded), key-split x2 ----------------
__global__ __launch_bounds__(512) void attn_mfma(
    const bf16* __restrict__ qkv, const bf16* __restrict__ vT,
    const int* __restrict__ mask, bf16* __restrict__ ctx) {
  __shared__ bf16 Ps[8][16][72];
  __shared__ float Obuf[4][16][64];
  __shared__ float Mbuf[4][16];
  __shared__ float Lbuf[4][16];
  const int h = blockIdx.y;
  const int q0 = blockIdx.x * 64;
  const int tid = threadIdx.x;
  const int wv = tid >> 6, lane = tid & 63;
  const int qg = wv & 3, half = wv >> 2;
  const int quad = lane >> 4, rsel = lane & 15;
  const int qw = q0 + qg * 16;

  const bf16* qp = &qkv[(size_t)(qw + rsel) * QKVN + h * CDH + quad * 8];
  bf16x8 qf0 = *(const bf16x8*)qp;
  bf16x8 qf1 = *(const bf16x8*)(qp + 32);

  float mi[4], li[4];
  f32x4 o[4] = {};
  #pragma unroll
  for (int r = 0; r < 4; ++r) { mi[r] = -1e30f; li[r] = 0.f; }

  const int kt0 = half ? 5 : 0, kt1 = half ? 9 : 5;
  #pragma unroll 1
  for (int kt = kt0; kt < kt1; ++kt) {
    int kbase = qw - CW + kt * 64;
    if (kbase + 63 < 0 || kbase >= CS) continue;

    f32x4 sc[4];
    #pragma unroll
    for (int nt = 0; nt < 4; ++nt) {
      int pp = kbase + nt * 16 + rsel;
      int ppc = min(max(pp, 0), CS - 1);
      const bf16* kp = &qkv[(size_t)ppc * QKVN + 768 + h * CDH + quad * 8];
      bf16x8 kf0 = *(const bf16x8*)kp;
      bf16x8 kf1 = *(const bf16x8*)(kp + 32);
      f32x4 z = {};
      z = __builtin_amdgcn_mfma_f32_16x16x32_bf16(qf0, kf0, z, 0, 0, 0);
      z = __builtin_amdgcn_mfma_f32_16x16x32_bf16(qf1, kf1, z, 0, 0, 0);
      sc[nt] = z;
    }
    float mx[4] = {-1e30f, -1e30f, -1e30f, -1e30f};
    #pragma unroll
    for (int nt = 0; nt < 4; ++nt) {
      int pp = kbase + nt * 16 + rsel;
      int ppc = min(max(pp, 0), CS - 1);
      bool kvld = (pp >= 0) && (pp < CS) && (mask[ppc] != 0);
      #pragma unroll
      for (int r = 0; r < 4; ++r) {
        int qr = qw + quad * 4 + r;
        float s = sc[nt][r] * 0.125f;
        bool band = (pp >= qr - CW) && (pp <= qr + CW);
        s = (kvld && band) ? s : -1e9f;
        sc[nt][r] = s;
        mx[r] = fmaxf(mx[r], s);
      }
    }
    #pragma unroll
    for (int r = 0; r < 4; ++r) {
      #pragma unroll
      for (int off = 1; off < 16; off <<= 1)
        mx[r] = fmaxf(mx[r], __shfl_xor(mx[r], off, 64));
    }
    float al[4], rs[4] = {};
    #pragma unroll
    for (int r = 0; r < 4; ++r) {
      float mn = fmaxf(mi[r], mx[r]);
      al[r] = __expf(mi[r] - mn);
      mi[r] = mn;
    }
    #pragma unroll
    for (int nt = 0; nt < 4; ++nt)
      #pragma unroll
      for (int r = 0; r < 4; ++r) {
        float p = __expf(sc[nt][r] - mi[r]);
        sc[nt][r] = p;
        rs[r] += p;
      }
    #pragma unroll
    for (int r = 0; r < 4; ++r) {
      #pragma unroll
      for (int off = 1; off < 16; off <<= 1)
        rs[r] += __shfl_xor(rs[r], off, 64);
      li[r] = li[r] * al[r] + rs[r];
    }
    #pragma unroll
    for (int d = 0; d < 4; ++d)
      #pragma unroll
      for (int r = 0; r < 4; ++r) o[d][r] *= al[r];
    #pragma unroll
    for (int nt = 0; nt < 4; ++nt)
      #pragma unroll
      for (int r = 0; r < 4; ++r)
        Ps[wv][quad * 4 + r][nt * 16 + rsel] = __float2bfloat16(sc[nt][r]);
    __asm__ volatile("s_waitcnt lgkmcnt(0)" ::: "memory");
    bf16x8 pf0 = *(const bf16x8*)&Ps[wv][rsel][quad * 8];
    bf16x8 pf1 = *(const bf16x8*)&Ps[wv][rsel][32 + quad * 8];
    int kc0 = min(max(kbase + quad * 8, 0), CS - 8);
    int kc1 = min(max(kbase + 32 + quad * 8, 0), CS - 8);
    #pragma unroll
    for (int d = 0; d < 4; ++d) {
      const bf16* vrow = &vT[(size_t)(h * CDH + d * 16 + rsel) * CS];
      bf16x8 vf0 = *(const bf16x8*)(vrow + kc0);
      bf16x8 vf1 = *(const bf16x8*)(vrow + kc1);
      o[d] = __builtin_amdgcn_mfma_f32_16x16x32_bf16(pf0, vf0, o[d], 0, 0, 0);
      o[d] = __builtin_amdgcn_mfma_f32_16x16x32_bf16(pf1, vf1, o[d], 0, 0, 0);
    }
  }

  if (half == 1) {
    #pragma unroll
    for (int d = 0; d < 4; ++d)
      #pragma unroll
      for (int r = 0; r < 4; ++r)
        Obuf[qg][quad * 4 + r][d * 16 + rsel] = o[d][r];
    if (rsel == 0) {
      #pragma unroll
      for (int r = 0; r < 4; ++r) {
        Mbuf[qg][quad * 4 + r] = mi[r];
        Lbuf[qg][quad * 4 + r] = li[r];
      }
    }
  }
  __syncthreads();
  if (half == 0) {
    #pragma unroll
    for (int r = 0; r < 4; ++r) {
      int row = quad * 4 + r;
      float m1 = Mbuf[qg][row], l1 = Lbuf[qg][row];
      float mn = fmaxf(mi[r], m1);
      float a0 = __expf(mi[r] - mn);
      float a1 = __expf(m1 - mn);
      float inv = 1.0f / (li[r] * a0 + l1 * a1);
      #pragma unroll
      for (int d = 0; d < 4; ++d) {
        float val = (o[d][r] * a0 + Obuf[qg][row][d * 16 + rsel] * a1) * inv;
        ctx[(size_t)(qw + row) * CD + h * CDH + d * 16 + rsel] = __float2bfloat16(val);
      }
    }
  }
}

// ---------------- xout = LN(xin + sum_p g[p](bf16)); also writes xb ----------------
template<int P>
__global__ __launch_bounds__(256) void add_ln_kernel(
    const bf16* __restrict__ g, const float* __restrict__ xin,
    float* __restrict__ xout, bf16* __restrict__ xb,
    const float* __restrict__ gs, const float* __restrict__ gb) {
  __shared__ float red[4];
  int srow = blockIdx.x;
  float v[3];
  #pragma unroll
  for (int i = 0; i < 3; ++i) {
    int d = threadIdx.x + i * 256;
    size_t idx = (size_t)srow * CD + d;
    float a = xin[idx];
    #pragma unroll
    for (int p = 0; p < P; ++p) a += __bfloat162float(g[p * SDC + idx]);
    v[i] = a;
  }
  float sum = v[0] + v[1] + v[2];
  sum = block_reduce_sum(sum, red);
  float mean = sum * (1.0f / CD);
  float sq = 0.f;
  #pragma unroll
  for (int i = 0; i < 3; ++i) { float c = v[i] - mean; sq += c * c; }
  sq = block_reduce_sum(sq, red);
  float rstd = rsqrtf(sq * (1.0f / CD) + 1e-5f);
  #pragma unroll
  for (int i = 0; i < 3; ++i) {
    int d = threadIdx.x + i * 256;
    float o = (v[i] - mean) * rstd * gs[d] + gb[d];
    xout[(size_t)srow * CD + d] = o;
    xb[(size_t)srow * CD + d] = __float2bfloat16(o);
  }
}

// ---------------- pooled = tanh(x[0] @ pool_W + pool_b) ----------------
__global__ __launch_bounds__(256) void pool_kernel(
    const float* __restrict__ x, const float* __restrict__ Wp,
    const float* __restrict__ bp, float* __restrict__ out) {
  __shared__ float xs[CD];
  __shared__ float red[4][64];
  int t = threadIdx.x;
  for (int i = t; i < CD; i += 256) xs[i] = x[i];
  __syncthreads();
  int n = blockIdx.x * 64 + (t & 63);
  int kp = t >> 6;
  float acc = 0.f;
  #pragma unroll 4
  for (int kk = kp * 192; kk < kp * 192 + 192; ++kk)
    acc = fmaf(xs[kk], Wp[(size_t)kk * CD + n], acc);
  red[kp][t & 63] = acc;
  __syncthreads();
  if (t < 64) {
    int nn = blockIdx.x * 64 + t;
    out[nn] = tanhf(red[0][t] + red[1][t] + red[2][t] + red[3][t] + bp[nn]);
  }
}

extern "C" void kernel_launch(void* const* d_in, const int* in_sizes, int n_in,
                              void* d_out, int out_size, void* d_ws, size_t ws_size,
                              hipStream_t stream) {
  const int*   ids   = (const int*)d_in[0];
  const int*   mask  = (const int*)d_in[1];
  const float* wemb  = (const float*)d_in[2];
  const float* pemb  = (const float*)d_in[3];
  const float* temb  = (const float*)d_in[4];
  const float* elns  = (const float*)d_in[5];
  const float* elnb  = (const float*)d_in[6];
  const float* Wqkv  = (const float*)d_in[7];
  const float* bqkv  = (const float*)d_in[8];
  const float* Wo    = (const float*)d_in[9];
  const float* bo    = (const float*)d_in[10];
  const float* ln1s  = (const float*)d_in[11];
  const float* ln1b  = (const float*)d_in[12];
  const float* W1    = (const float*)d_in[13];
  const float* b1    = (const float*)d_in[14];
  const float* W2    = (const float*)d_in[15];
  const float* b2    = (const float*)d_in[16];
  const float* ln2s  = (const float*)d_in[17];
  const float* ln2b  = (const float*)d_in[18];
  const float* poolW = (const float*)d_in[19];
  const float* poolb = (const float*)d_in[20];

  const size_t SD = SDC;
  const size_t SF = (size_t)CS * CF;

  char* w = (char*)d_ws;
  float* x    = (float*)w; w += SD * 4;
  bf16*  xb   = (bf16*)w;  w += SD * 2;
  bf16*  qkv  = (bf16*)w;  w += (size_t)CS * QKVN * 2;
  bf16*  vT   = (bf16*)w;  w += SD * 2;
  bf16*  ctxb = (bf16*)w;  w += SD * 2;
  bf16*  t1b  = (bf16*)w;  w += SF * 2;
  bf16*  t2   = (bf16*)w;  w += SD * 2 * 4;   // 4 split-K bf16 partials
  bf16* WqkvT = (bf16*)w;  w += (size_t)CL * QKVN * CD * 2;
  bf16* WoT   = (bf16*)w;  w += (size_t)CL * CD * CD * 2;
  bf16* W1T   = (bf16*)w;  w += (size_t)CL * CF * CD * 2;
  bf16* W2T   = (bf16*)w;  w += (size_t)CL * CD * CF * 2;

  transpose_all<<<13824, 256, 0, stream>>>(Wqkv, Wo, W1, W2, WqkvT, WoT, W1T, W2T);
  embed_ln_kernel<<<CS, 256, 0, stream>>>(ids, mask, wemb, pemb, temb, elns, elnb, x, xb);

  for (int l = 0; l < CL; ++l) {
    gemm_mfma<0,1,1,1><<<dim3(QKVN/128, CS/128), 256, 0, stream>>>(
        xb, WqkvT + (size_t)l * QKVN * CD, bqkv + (size_t)l * 3 * CD, qkv, vT, CS, QKVN, CD);
    attn_mfma<<<dim3(CS/64, CH), 512, 0, stream>>>(qkv, vT, mask, ctxb);
    gemm_mfma<0,0,2,0><<<dim3(CD/128, CS/128, 2), 256, 0, stream>>>(
        ctxb, WoT + (size_t)l * CD * CD, bo + (size_t)l * CD, t2, nullptr, CS, CD, CD);
    add_ln_kernel<2><<<CS, 256, 0, stream>>>(t2, x, x, xb,
        ln1s + (size_t)l * CD, ln1b + (size_t)l * CD);
    gemm_mfma<1,1,1,0><<<dim3(CF/128, CS/128), 256, 0, stream>>>(
        xb, W1T + (size_t)l * CF * CD, b1 + (size_t)l * CF, t1b, nullptr, CS, CF, CD);
    gemm_mfma<0,0,4,0><<<dim3(CD/128, CS/128, 4), 256, 0, stream>>>(
        t1b, W2T + (size_t)l * CD * CF, b2 + (size_t)l * CD, t2, nullptr, CS, CD, CF);
    float* lastx = (l == CL - 1) ? (float*)d_out : x;
    add_ln_kernel<4><<<CS, 256, 0, stream>>>(t2, x, lastx, xb,
        ln2s + (size_t)l * CD, ln2b + (size_t)l * CD);
  }

  pool_kernel<<<12, 256, 0, stream>>>((float*)d_out, poolW, poolb, (float*)d_out + SD);
}